// Round 1
// baseline (2914.711 us; speedup 1.0000x reference)
//
#include <hip/hip_runtime.h>
#include <cstdint>
#include <cstddef>

#define DF 64          // feature dim
#define NREL 8         // relations

// ---------------------------------------------------------------------------
// transform: h[r][n][f] = sum_d x[n][d] * W[r][d][f]
// block: 128 threads, tile = 128 nodes x 64 f, per-thread 8n x 8f
// ---------------------------------------------------------------------------
__global__ __launch_bounds__(128) void rgcn_transform(
    const float* __restrict__ x,    // [N, 64]
    const float* __restrict__ Wc,   // chunk base: [rc, 64, 64]
    float* __restrict__ h,          // [rc, N, 64]
    int N)
{
  const int r = blockIdx.y;
  const float* W = Wc + (size_t)r * DF * DF;
  float* out = h + (size_t)r * N * DF;

  __shared__ float Ws[DF * DF];       // [d][f]
  __shared__ float Xs[128 * 65];      // [n][d], stride 65 (bank-conflict pad)

  const int tid = threadIdx.x;
  const int n0 = blockIdx.x * 128;
  const int nrem = N - n0;            // may be < 128 in last block

  // load W (4096 floats) coalesced as float4
  {
    const float4* Wv = (const float4*)W;
    float4* Wsv = (float4*)Ws;
#pragma unroll
    for (int j = 0; j < 8; ++j) Wsv[tid + j * 128] = Wv[tid + j * 128];
  }
  // load x tile (128x64) coalesced, scatter into padded LDS
#pragma unroll
  for (int j = 0; j < 16; ++j) {
    int idx = tid + j * 128;          // 0..2047 float4 index
    int n = idx >> 4;
    int c4 = (idx & 15) * 4;
    float4 v = make_float4(0.f, 0.f, 0.f, 0.f);
    if (n < nrem) v = *(const float4*)&x[(size_t)(n0 + n) * DF + c4];
    float* p = &Xs[n * 65 + c4];
    p[0] = v.x; p[1] = v.y; p[2] = v.z; p[3] = v.w;
  }
  __syncthreads();

  const int fg = (tid & 7) * 8;       // f base (8 f per thread)
  const int ng = (tid >> 3) * 8;      // n base (8 n per thread)

  float4 a0[8], a1[8];
#pragma unroll
  for (int i = 0; i < 8; ++i) {
    a0[i] = make_float4(0.f, 0.f, 0.f, 0.f);
    a1[i] = make_float4(0.f, 0.f, 0.f, 0.f);
  }

#pragma unroll 4
  for (int d = 0; d < DF; ++d) {
    float4 w0 = *(const float4*)&Ws[d * DF + fg];
    float4 w1 = *(const float4*)&Ws[d * DF + fg + 4];
#pragma unroll
    for (int i = 0; i < 8; ++i) {
      float xv = Xs[(ng + i) * 65 + d];
      a0[i].x += xv * w0.x; a0[i].y += xv * w0.y;
      a0[i].z += xv * w0.z; a0[i].w += xv * w0.w;
      a1[i].x += xv * w1.x; a1[i].y += xv * w1.y;
      a1[i].z += xv * w1.z; a1[i].w += xv * w1.w;
    }
  }

#pragma unroll
  for (int i = 0; i < 8; ++i) {
    int n = ng + i;
    if (n < nrem) {
      float* op = out + (size_t)(n0 + n) * DF + fg;
      *(float4*)op = a0[i];
      *(float4*)(op + 4) = a1[i];
    }
  }
}

// ---------------------------------------------------------------------------
// scatter: out[dst[e]][:] += h[et[e]][src[e]][:]   (atomic)
// 16 threads per edge, float4 read + 4 scalar atomics each
// ---------------------------------------------------------------------------
__global__ __launch_bounds__(256) void rgcn_scatter(
    const int* __restrict__ src, const int* __restrict__ dst,
    const int* __restrict__ et,
    const float* __restrict__ h,   // [rc, N, 64]
    float* __restrict__ out,       // [N, 64]
    int E, int N, int r0, int r1)
{
  long long g = (long long)blockIdx.x * 256 + threadIdx.x;
  int e = (int)(g >> 4);
  if (e >= E) return;
  int r = et[e];
  if (r < r0 || r >= r1) return;
  int f4 = ((int)g & 15) * 4;
  int s = src[e];
  int d = dst[e];
  const float4 v = *(const float4*)&h[(((size_t)(r - r0) * N + s) << 6) + f4];
  float* o = out + ((size_t)d << 6) + f4;
  atomicAdd(o + 0, v.x);
  atomicAdd(o + 1, v.y);
  atomicAdd(o + 2, v.z);
  atomicAdd(o + 3, v.w);
}

// ---------------------------------------------------------------------------
// epilogue: out[n][f] = maybe_relu(out[n][f] + sum_d x[n][d]*root[d][f] + b[f])
// same tiling as transform
// ---------------------------------------------------------------------------
__global__ __launch_bounds__(128) void rgcn_root_epilogue(
    const float* __restrict__ x,
    const float* __restrict__ root,
    const float* __restrict__ bias,
    float* __restrict__ out, int N, int do_relu)
{
  __shared__ float Ws[DF * DF];
  __shared__ float Xs[128 * 65];

  const int tid = threadIdx.x;
  const int n0 = blockIdx.x * 128;
  const int nrem = N - n0;

  {
    const float4* Wv = (const float4*)root;
    float4* Wsv = (float4*)Ws;
#pragma unroll
    for (int j = 0; j < 8; ++j) Wsv[tid + j * 128] = Wv[tid + j * 128];
  }
#pragma unroll
  for (int j = 0; j < 16; ++j) {
    int idx = tid + j * 128;
    int n = idx >> 4;
    int c4 = (idx & 15) * 4;
    float4 v = make_float4(0.f, 0.f, 0.f, 0.f);
    if (n < nrem) v = *(const float4*)&x[(size_t)(n0 + n) * DF + c4];
    float* p = &Xs[n * 65 + c4];
    p[0] = v.x; p[1] = v.y; p[2] = v.z; p[3] = v.w;
  }
  __syncthreads();

  const int fg = (tid & 7) * 8;
  const int ng = (tid >> 3) * 8;

  float4 a0[8], a1[8];
#pragma unroll
  for (int i = 0; i < 8; ++i) {
    a0[i] = make_float4(0.f, 0.f, 0.f, 0.f);
    a1[i] = make_float4(0.f, 0.f, 0.f, 0.f);
  }

#pragma unroll 4
  for (int d = 0; d < DF; ++d) {
    float4 w0 = *(const float4*)&Ws[d * DF + fg];
    float4 w1 = *(const float4*)&Ws[d * DF + fg + 4];
#pragma unroll
    for (int i = 0; i < 8; ++i) {
      float xv = Xs[(ng + i) * 65 + d];
      a0[i].x += xv * w0.x; a0[i].y += xv * w0.y;
      a0[i].z += xv * w0.z; a0[i].w += xv * w0.w;
      a1[i].x += xv * w1.x; a1[i].y += xv * w1.y;
      a1[i].z += xv * w1.z; a1[i].w += xv * w1.w;
    }
  }

  float4 bb0 = *(const float4*)&bias[fg];
  float4 bb1 = *(const float4*)&bias[fg + 4];

#pragma unroll
  for (int i = 0; i < 8; ++i) {
    int n = ng + i;
    if (n < nrem) {
      float* op = out + (size_t)(n0 + n) * DF + fg;
      float4 o0 = *(float4*)op;
      float4 o1 = *(float4*)(op + 4);
      o0.x += a0[i].x + bb0.x; o0.y += a0[i].y + bb0.y;
      o0.z += a0[i].z + bb0.z; o0.w += a0[i].w + bb0.w;
      o1.x += a1[i].x + bb1.x; o1.y += a1[i].y + bb1.y;
      o1.z += a1[i].z + bb1.z; o1.w += a1[i].w + bb1.w;
      if (do_relu) {
        o0.x = fmaxf(o0.x, 0.f); o0.y = fmaxf(o0.y, 0.f);
        o0.z = fmaxf(o0.z, 0.f); o0.w = fmaxf(o0.w, 0.f);
        o1.x = fmaxf(o1.x, 0.f); o1.y = fmaxf(o1.y, 0.f);
        o1.z = fmaxf(o1.z, 0.f); o1.w = fmaxf(o1.w, 0.f);
      }
      *(float4*)op = o0;
      *(float4*)(op + 4) = o1;
    }
  }
}

// ---------------------------------------------------------------------------
extern "C" void kernel_launch(void* const* d_in, const int* in_sizes, int n_in,
                              void* d_out, int out_size, void* d_ws, size_t ws_size,
                              hipStream_t stream) {
  const int* adj    = (const int*)d_in[0];    // [2, E]
  const float* feat = (const float*)d_in[1];  // [N, 64]
  const int* et     = (const int*)d_in[2];    // [E]
  const float* W1   = (const float*)d_in[3];  // [8, 64, 64]
  const float* rt1  = (const float*)d_in[4];  // [64, 64]
  const float* b1   = (const float*)d_in[5];  // [64]
  const float* W2   = (const float*)d_in[6];
  const float* rt2  = (const float*)d_in[7];
  const float* b2   = (const float*)d_in[8];

  const int E = in_sizes[0] / 2;
  const int N = in_sizes[1] / DF;
  const int* srcp = adj;
  const int* dstp = adj + E;

  float* out = (float*)d_out;
  const size_t ND = (size_t)N * DF;

  // workspace: h chunk [RC, N, 64] + xmid [N, 64]
  size_t avail_f = ws_size / sizeof(float);
  int RC = 1;
  if (avail_f > 2 * ND) {
    size_t rc = (avail_f - ND) / ND;
    RC = rc >= NREL ? NREL : (int)rc;
  }
  float* h = (float*)d_ws;
  float* xmid = h + (size_t)RC * ND;

  const int nblk = (N + 127) / 128;
  const int sblk = (int)(((size_t)E * 16 + 255) / 256);

  for (int layer = 0; layer < 2; ++layer) {
    const float* xin = layer ? xmid : feat;
    const float* W   = layer ? W2 : W1;
    const float* rt  = layer ? rt2 : rt1;
    const float* bs  = layer ? b2 : b1;
    float* o         = layer ? out : xmid;

    hipMemsetAsync(o, 0, ND * sizeof(float), stream);
    for (int r0 = 0; r0 < NREL; r0 += RC) {
      int rc = (NREL - r0) < RC ? (NREL - r0) : RC;
      rgcn_transform<<<dim3(nblk, rc), 128, 0, stream>>>(
          xin, W + (size_t)r0 * DF * DF, h, N);
      rgcn_scatter<<<sblk, 256, 0, stream>>>(
          srcp, dstp, et, h, o, E, N, r0, r0 + rc);
    }
    rgcn_root_epilogue<<<nblk, 128, 0, stream>>>(xin, rt, bs, o, N, layer == 0 ? 1 : 0);
  }
}

// Round 2
// 617.130 us; speedup vs baseline: 4.7230x; 4.7230x over previous
//
#include <hip/hip_runtime.h>
#include <cstdint>
#include <cstddef>

#define DF 64          // feature dim
#define NREL 8         // relations

// ---------------------------------------------------------------------------
// transform: h[r][n][f] = sum_d x[n][d] * W[r][d][f]
// block: 128 threads, tile = 128 nodes x 64 f, per-thread 8n x 8f
// ---------------------------------------------------------------------------
__global__ __launch_bounds__(128) void rgcn_transform(
    const float* __restrict__ x,    // [N, 64]
    const float* __restrict__ Wc,   // chunk base: [rc, 64, 64]
    float* __restrict__ h,          // [rc, N, 64]
    int N)
{
  const int r = blockIdx.y;
  const float* W = Wc + (size_t)r * DF * DF;
  float* out = h + (size_t)r * N * DF;

  __shared__ float Ws[DF * DF];       // [d][f]
  __shared__ float Xs[128 * 65];      // [n][d], stride 65 (bank-conflict pad)

  const int tid = threadIdx.x;
  const int n0 = blockIdx.x * 128;
  const int nrem = N - n0;

  {
    const float4* Wv = (const float4*)W;
    float4* Wsv = (float4*)Ws;
#pragma unroll
    for (int j = 0; j < 8; ++j) Wsv[tid + j * 128] = Wv[tid + j * 128];
  }
#pragma unroll
  for (int j = 0; j < 16; ++j) {
    int idx = tid + j * 128;
    int n = idx >> 4;
    int c4 = (idx & 15) * 4;
    float4 v = make_float4(0.f, 0.f, 0.f, 0.f);
    if (n < nrem) v = *(const float4*)&x[(size_t)(n0 + n) * DF + c4];
    float* p = &Xs[n * 65 + c4];
    p[0] = v.x; p[1] = v.y; p[2] = v.z; p[3] = v.w;
  }
  __syncthreads();

  const int fg = (tid & 7) * 8;
  const int ng = (tid >> 3) * 8;

  float4 a0[8], a1[8];
#pragma unroll
  for (int i = 0; i < 8; ++i) {
    a0[i] = make_float4(0.f, 0.f, 0.f, 0.f);
    a1[i] = make_float4(0.f, 0.f, 0.f, 0.f);
  }

#pragma unroll 4
  for (int d = 0; d < DF; ++d) {
    float4 w0 = *(const float4*)&Ws[d * DF + fg];
    float4 w1 = *(const float4*)&Ws[d * DF + fg + 4];
#pragma unroll
    for (int i = 0; i < 8; ++i) {
      float xv = Xs[(ng + i) * 65 + d];
      a0[i].x += xv * w0.x; a0[i].y += xv * w0.y;
      a0[i].z += xv * w0.z; a0[i].w += xv * w0.w;
      a1[i].x += xv * w1.x; a1[i].y += xv * w1.y;
      a1[i].z += xv * w1.z; a1[i].w += xv * w1.w;
    }
  }

#pragma unroll
  for (int i = 0; i < 8; ++i) {
    int n = ng + i;
    if (n < nrem) {
      float* op = out + (size_t)(n0 + n) * DF + fg;
      *(float4*)op = a0[i];
      *(float4*)(op + 4) = a1[i];
    }
  }
}

// ---------------------------------------------------------------------------
// epilogue: val = x@root ; mode 0: out = val + b
//                          mode 1: out = relu(out + val + b)
//                          mode 2: out = out + val + b
// ---------------------------------------------------------------------------
__global__ __launch_bounds__(128) void rgcn_root_epilogue(
    const float* __restrict__ x,
    const float* __restrict__ root,
    const float* __restrict__ bias,
    float* __restrict__ out, int N, int mode)
{
  __shared__ float Ws[DF * DF];
  __shared__ float Xs[128 * 65];

  const int tid = threadIdx.x;
  const int n0 = blockIdx.x * 128;
  const int nrem = N - n0;

  {
    const float4* Wv = (const float4*)root;
    float4* Wsv = (float4*)Ws;
#pragma unroll
    for (int j = 0; j < 8; ++j) Wsv[tid + j * 128] = Wv[tid + j * 128];
  }
#pragma unroll
  for (int j = 0; j < 16; ++j) {
    int idx = tid + j * 128;
    int n = idx >> 4;
    int c4 = (idx & 15) * 4;
    float4 v = make_float4(0.f, 0.f, 0.f, 0.f);
    if (n < nrem) v = *(const float4*)&x[(size_t)(n0 + n) * DF + c4];
    float* p = &Xs[n * 65 + c4];
    p[0] = v.x; p[1] = v.y; p[2] = v.z; p[3] = v.w;
  }
  __syncthreads();

  const int fg = (tid & 7) * 8;
  const int ng = (tid >> 3) * 8;

  float4 a0[8], a1[8];
#pragma unroll
  for (int i = 0; i < 8; ++i) {
    a0[i] = make_float4(0.f, 0.f, 0.f, 0.f);
    a1[i] = make_float4(0.f, 0.f, 0.f, 0.f);
  }

#pragma unroll 4
  for (int d = 0; d < DF; ++d) {
    float4 w0 = *(const float4*)&Ws[d * DF + fg];
    float4 w1 = *(const float4*)&Ws[d * DF + fg + 4];
#pragma unroll
    for (int i = 0; i < 8; ++i) {
      float xv = Xs[(ng + i) * 65 + d];
      a0[i].x += xv * w0.x; a0[i].y += xv * w0.y;
      a0[i].z += xv * w0.z; a0[i].w += xv * w0.w;
      a1[i].x += xv * w1.x; a1[i].y += xv * w1.y;
      a1[i].z += xv * w1.z; a1[i].w += xv * w1.w;
    }
  }

  float4 bb0 = *(const float4*)&bias[fg];
  float4 bb1 = *(const float4*)&bias[fg + 4];

#pragma unroll
  for (int i = 0; i < 8; ++i) {
    int n = ng + i;
    if (n < nrem) {
      float* op = out + (size_t)(n0 + n) * DF + fg;
      float4 o0, o1;
      if (mode == 0) {
        o0 = make_float4(a0[i].x + bb0.x, a0[i].y + bb0.y,
                         a0[i].z + bb0.z, a0[i].w + bb0.w);
        o1 = make_float4(a1[i].x + bb1.x, a1[i].y + bb1.y,
                         a1[i].z + bb1.z, a1[i].w + bb1.w);
      } else {
        o0 = *(float4*)op;
        o1 = *(float4*)(op + 4);
        o0.x += a0[i].x + bb0.x; o0.y += a0[i].y + bb0.y;
        o0.z += a0[i].z + bb0.z; o0.w += a0[i].w + bb0.w;
        o1.x += a1[i].x + bb1.x; o1.y += a1[i].y + bb1.y;
        o1.z += a1[i].z + bb1.z; o1.w += a1[i].w + bb1.w;
        if (mode == 1) {
          o0.x = fmaxf(o0.x, 0.f); o0.y = fmaxf(o0.y, 0.f);
          o0.z = fmaxf(o0.z, 0.f); o0.w = fmaxf(o0.w, 0.f);
          o1.x = fmaxf(o1.x, 0.f); o1.y = fmaxf(o1.y, 0.f);
          o1.z = fmaxf(o1.z, 0.f); o1.w = fmaxf(o1.w, 0.f);
        }
      }
      *(float4*)op = o0;
      *(float4*)(op + 4) = o1;
    }
  }
}

// ---------------------------------------------------------------------------
// CSR build kernels
// ---------------------------------------------------------------------------
__global__ __launch_bounds__(256) void csr_count(
    const int* __restrict__ dst, int* __restrict__ cnt, int E)
{
  int e = blockIdx.x * 256 + threadIdx.x;
  if (e < E) atomicAdd(&cnt[dst[e]], 1);
}

// single block, 1024 threads: exclusive scan of cnt[N] -> row_ptr[N+1],
// and cursor[i] = row_ptr[i] (cnt and cursor are the SAME buffer).
__global__ __launch_bounds__(1024) void csr_scan(
    int* __restrict__ cnt_cursor, int* __restrict__ row_ptr, int N, int E)
{
  __shared__ int sh[1024];
  const int t = threadIdx.x;
  const int chunk = (N + 1023) / 1024;
  const int base = t * chunk;

  int sum = 0;
  for (int i = 0; i < chunk; ++i) {
    int idx = base + i;
    if (idx < N) sum += cnt_cursor[idx];
  }
  sh[t] = sum;
  __syncthreads();
  for (int off = 1; off < 1024; off <<= 1) {
    int v = (t >= off) ? sh[t - off] : 0;
    __syncthreads();
    sh[t] += v;
    __syncthreads();
  }
  int run = sh[t] - sum;   // exclusive prefix of this thread's chunk
  for (int i = 0; i < chunk; ++i) {
    int idx = base + i;
    if (idx < N) {
      int c = cnt_cursor[idx];
      row_ptr[idx] = run;
      cnt_cursor[idx] = run;   // becomes the fill cursor
      run += c;
    }
  }
  if (t == 1023) row_ptr[N] = E;
}

__global__ __launch_bounds__(256) void csr_fill(
    const int* __restrict__ src, const int* __restrict__ dst,
    const int* __restrict__ et, int* __restrict__ cursor,
    unsigned int* __restrict__ sorted, int E)
{
  int e = blockIdx.x * 256 + threadIdx.x;
  if (e >= E) return;
  int d = dst[e];
  int pos = atomicAdd(&cursor[d], 1);
  sorted[pos] = (unsigned int)src[e] | ((unsigned int)et[e] << 24);
}

// ---------------------------------------------------------------------------
// gather: out[n][:] (+)= sum_{e in-edges(n)} h[rel(e)][src(e)][:]
// 16 lanes per node, float4 per lane, no atomics.
// ---------------------------------------------------------------------------
__global__ __launch_bounds__(256) void rgcn_gather(
    const unsigned int* __restrict__ sorted,
    const int* __restrict__ row_ptr,
    const float* __restrict__ h,   // [8, N, 64]
    float* __restrict__ out,       // [N, 64]
    int N, int do_relu)
{
  const int t = threadIdx.x;
  const int node = blockIdx.x * 16 + (t >> 4);
  if (node >= N) return;
  const int l4 = (t & 15) * 4;

  int p = row_ptr[node];
  const int pe = row_ptr[node + 1];

  float4 acc = make_float4(0.f, 0.f, 0.f, 0.f);
  for (; p + 1 < pe; p += 2) {
    unsigned int pa = sorted[p];
    unsigned int pb = sorted[p + 1];
    const float4 va = *(const float4*)&h[
        (((size_t)(pa >> 24) * N + (pa & 0xFFFFFFu)) << 6) + l4];
    const float4 vb = *(const float4*)&h[
        (((size_t)(pb >> 24) * N + (pb & 0xFFFFFFu)) << 6) + l4];
    acc.x += va.x + vb.x; acc.y += va.y + vb.y;
    acc.z += va.z + vb.z; acc.w += va.w + vb.w;
  }
  if (p < pe) {
    unsigned int pa = sorted[p];
    const float4 va = *(const float4*)&h[
        (((size_t)(pa >> 24) * N + (pa & 0xFFFFFFu)) << 6) + l4];
    acc.x += va.x; acc.y += va.y; acc.z += va.z; acc.w += va.w;
  }

  float* o = out + ((size_t)node << 6) + l4;
  float4 cur = *(float4*)o;
  cur.x += acc.x; cur.y += acc.y; cur.z += acc.z; cur.w += acc.w;
  if (do_relu) {
    cur.x = fmaxf(cur.x, 0.f); cur.y = fmaxf(cur.y, 0.f);
    cur.z = fmaxf(cur.z, 0.f); cur.w = fmaxf(cur.w, 0.f);
  }
  *(float4*)o = cur;
}

// ---------------------------------------------------------------------------
// fallback atomic scatter (only if ws too small for CSR path)
// ---------------------------------------------------------------------------
__global__ __launch_bounds__(256) void rgcn_scatter(
    const int* __restrict__ src, const int* __restrict__ dst,
    const int* __restrict__ et,
    const float* __restrict__ h,
    float* __restrict__ out,
    int E, int N, int r0, int r1)
{
  long long g = (long long)blockIdx.x * 256 + threadIdx.x;
  int e = (int)(g >> 4);
  if (e >= E) return;
  int r = et[e];
  if (r < r0 || r >= r1) return;
  int f4 = ((int)g & 15) * 4;
  int s = src[e];
  int d = dst[e];
  const float4 v = *(const float4*)&h[(((size_t)(r - r0) * N + s) << 6) + f4];
  float* o = out + ((size_t)d << 6) + f4;
  atomicAdd(o + 0, v.x);
  atomicAdd(o + 1, v.y);
  atomicAdd(o + 2, v.z);
  atomicAdd(o + 3, v.w);
}

// ---------------------------------------------------------------------------
extern "C" void kernel_launch(void* const* d_in, const int* in_sizes, int n_in,
                              void* d_out, int out_size, void* d_ws, size_t ws_size,
                              hipStream_t stream) {
  const int* adj    = (const int*)d_in[0];    // [2, E]
  const float* feat = (const float*)d_in[1];  // [N, 64]
  const int* et     = (const int*)d_in[2];    // [E]
  const float* W1   = (const float*)d_in[3];
  const float* rt1  = (const float*)d_in[4];
  const float* b1   = (const float*)d_in[5];
  const float* W2   = (const float*)d_in[6];
  const float* rt2  = (const float*)d_in[7];
  const float* b2   = (const float*)d_in[8];

  const int E = in_sizes[0] / 2;
  const int N = in_sizes[1] / DF;
  const int* srcp = adj;
  const int* dstp = adj + E;

  float* out = (float*)d_out;
  const size_t ND = (size_t)N * DF;
  const int nblk = (N + 127) / 128;

  // CSR-path workspace layout
  const size_t need_csr =
      (8 * ND + (size_t)E + 2 * (size_t)N + 2) * sizeof(float);

  if (ws_size >= need_csr) {
    float* h = (float*)d_ws;                         // [8, N, 64]
    unsigned int* sorted = (unsigned int*)(h + 8 * ND);  // [E]
    int* row_ptr = (int*)(sorted + E);               // [N+1]
    int* cursor  = row_ptr + (N + 1);                // [N] (cnt then cursor)

    // ---- build CSR once (same graph for both layers) ----
    hipMemsetAsync(cursor, 0, (size_t)N * sizeof(int), stream);
    csr_count<<<(E + 255) / 256, 256, 0, stream>>>(dstp, cursor, E);
    csr_scan<<<1, 1024, 0, stream>>>(cursor, row_ptr, N, E);
    csr_fill<<<(E + 255) / 256, 256, 0, stream>>>(srcp, dstp, et, cursor, sorted, E);

    const int gblk = (N + 15) / 16;

    // ---- layer 1: out = relu( gather(h1) + feat@rt1 + b1 ) ----
    rgcn_transform<<<dim3(nblk, NREL), 128, 0, stream>>>(feat, W1, h, N);
    rgcn_root_epilogue<<<nblk, 128, 0, stream>>>(feat, rt1, b1, out, N, 0);
    rgcn_gather<<<gblk, 256, 0, stream>>>(sorted, row_ptr, h, out, N, 1);

    // ---- layer 2: out = gather(h2) + out@rt2 + b2 ----
    rgcn_transform<<<dim3(nblk, NREL), 128, 0, stream>>>(out, W2, h, N);
    rgcn_root_epilogue<<<nblk, 128, 0, stream>>>(out, rt2, b2, out, N, 0);
    rgcn_gather<<<gblk, 256, 0, stream>>>(sorted, row_ptr, h, out, N, 0);
    return;
  }

  // ---------------- fallback: atomic scatter (round-1 path) ----------------
  size_t avail_f = ws_size / sizeof(float);
  int RC = 1;
  if (avail_f > 2 * ND) {
    size_t rc = (avail_f - ND) / ND;
    RC = rc >= NREL ? NREL : (int)rc;
  }
  float* h = (float*)d_ws;
  float* xmid = h + (size_t)RC * ND;
  const int sblk = (int)(((size_t)E * 16 + 255) / 256);

  for (int layer = 0; layer < 2; ++layer) {
    const float* xin = layer ? xmid : feat;
    const float* W   = layer ? W2 : W1;
    const float* rt  = layer ? rt2 : rt1;
    const float* bs  = layer ? b2 : b1;
    float* o         = layer ? out : xmid;

    hipMemsetAsync(o, 0, ND * sizeof(float), stream);
    for (int r0 = 0; r0 < NREL; r0 += RC) {
      int rc = (NREL - r0) < RC ? (NREL - r0) : RC;
      rgcn_transform<<<dim3(nblk, rc), 128, 0, stream>>>(
          xin, W + (size_t)r0 * DF * DF, h, N);
      rgcn_scatter<<<sblk, 256, 0, stream>>>(
          srcp, dstp, et, h, o, E, N, r0, r0 + rc);
    }
    rgcn_root_epilogue<<<nblk, 128, 0, stream>>>(xin, rt, bs, o, N,
                                                 layer == 0 ? 1 : 2);
  }
}

// Round 3
// 454.192 us; speedup vs baseline: 6.4173x; 1.3587x over previous
//
#include <hip/hip_runtime.h>
#include <cstdint>
#include <cstddef>

#define DF 64          // feature dim
#define NREL 8         // relations

// ---- bf16 helpers (RNE) ---------------------------------------------------
static __device__ __forceinline__ unsigned short f2bf(float f) {
  unsigned int u = __float_as_uint(f);
  u += 0x7FFFu + ((u >> 16) & 1u);
  return (unsigned short)(u >> 16);
}
static __device__ __forceinline__ float bf2f(unsigned short s) {
  return __uint_as_float((unsigned int)s << 16);
}

// ---------------------------------------------------------------------------
// transform: h[r][n][f] = sum_d x[n][d] * W[r][d][f]   (h stored bf16)
// blockIdx.y == 8 (when launched with ny=9): out[n][f] = x@root + bias (fp32)
// block: 128 threads, tile = 128 nodes x 64 f, per-thread 8n x 8f
// ---------------------------------------------------------------------------
__global__ __launch_bounds__(128) void rgcn_transform(
    const float* __restrict__ x,     // [N, 64]
    const float* __restrict__ Wc,    // [rc, 64, 64]
    const float* __restrict__ root,  // [64, 64] or null
    const float* __restrict__ bias,  // [64] or null
    unsigned short* __restrict__ hb, // [rc, N, 64] bf16
    float* __restrict__ out,         // [N, 64] fp32 (root path)
    int N)
{
  const int r = blockIdx.y;
  const bool is_root = (r == 8);
  const float* W = is_root ? root : (Wc + (size_t)r * DF * DF);

  __shared__ float Ws[DF * DF];       // [d][f]
  __shared__ float Xs[128 * 65];      // [n][d], stride 65

  const int tid = threadIdx.x;
  const int n0 = blockIdx.x * 128;
  const int nrem = N - n0;

  {
    const float4* Wv = (const float4*)W;
    float4* Wsv = (float4*)Ws;
#pragma unroll
    for (int j = 0; j < 8; ++j) Wsv[tid + j * 128] = Wv[tid + j * 128];
  }
#pragma unroll
  for (int j = 0; j < 16; ++j) {
    int idx = tid + j * 128;
    int n = idx >> 4;
    int c4 = (idx & 15) * 4;
    float4 v = make_float4(0.f, 0.f, 0.f, 0.f);
    if (n < nrem) v = *(const float4*)&x[(size_t)(n0 + n) * DF + c4];
    float* p = &Xs[n * 65 + c4];
    p[0] = v.x; p[1] = v.y; p[2] = v.z; p[3] = v.w;
  }
  __syncthreads();

  const int fg = (tid & 7) * 8;
  const int ng = (tid >> 3) * 8;

  float4 a0[8], a1[8];
#pragma unroll
  for (int i = 0; i < 8; ++i) {
    a0[i] = make_float4(0.f, 0.f, 0.f, 0.f);
    a1[i] = make_float4(0.f, 0.f, 0.f, 0.f);
  }

#pragma unroll 4
  for (int d = 0; d < DF; ++d) {
    float4 w0 = *(const float4*)&Ws[d * DF + fg];
    float4 w1 = *(const float4*)&Ws[d * DF + fg + 4];
#pragma unroll
    for (int i = 0; i < 8; ++i) {
      float xv = Xs[(ng + i) * 65 + d];
      a0[i].x += xv * w0.x; a0[i].y += xv * w0.y;
      a0[i].z += xv * w0.z; a0[i].w += xv * w0.w;
      a1[i].x += xv * w1.x; a1[i].y += xv * w1.y;
      a1[i].z += xv * w1.z; a1[i].w += xv * w1.w;
    }
  }

  if (is_root) {
    float4 bb0 = *(const float4*)&bias[fg];
    float4 bb1 = *(const float4*)&bias[fg + 4];
#pragma unroll
    for (int i = 0; i < 8; ++i) {
      int n = ng + i;
      if (n < nrem) {
        float* op = out + (size_t)(n0 + n) * DF + fg;
        *(float4*)op = make_float4(a0[i].x + bb0.x, a0[i].y + bb0.y,
                                   a0[i].z + bb0.z, a0[i].w + bb0.w);
        *(float4*)(op + 4) = make_float4(a1[i].x + bb1.x, a1[i].y + bb1.y,
                                         a1[i].z + bb1.z, a1[i].w + bb1.w);
      }
    }
  } else {
#pragma unroll
    for (int i = 0; i < 8; ++i) {
      int n = ng + i;
      if (n < nrem) {
        uint4 pk;
        pk.x = (unsigned)f2bf(a0[i].x) | ((unsigned)f2bf(a0[i].y) << 16);
        pk.y = (unsigned)f2bf(a0[i].z) | ((unsigned)f2bf(a0[i].w) << 16);
        pk.z = (unsigned)f2bf(a1[i].x) | ((unsigned)f2bf(a1[i].y) << 16);
        pk.w = (unsigned)f2bf(a1[i].z) | ((unsigned)f2bf(a1[i].w) << 16);
        unsigned short* op = hb + (((size_t)r * N + (n0 + n)) << 6) + fg;
        *(uint4*)op = pk;
      }
    }
  }
}

// ---------------------------------------------------------------------------
// epilogue (fp32): mode 0: out = x@root + b          (overwrite)
//                  mode 1: out = relu(out + x@root + b)
//                  mode 2: out = out + x@root + b
// ---------------------------------------------------------------------------
__global__ __launch_bounds__(128) void rgcn_root_epilogue(
    const float* __restrict__ x,
    const float* __restrict__ root,
    const float* __restrict__ bias,
    float* __restrict__ out, int N, int mode)
{
  __shared__ float Ws[DF * DF];
  __shared__ float Xs[128 * 65];

  const int tid = threadIdx.x;
  const int n0 = blockIdx.x * 128;
  const int nrem = N - n0;

  {
    const float4* Wv = (const float4*)root;
    float4* Wsv = (float4*)Ws;
#pragma unroll
    for (int j = 0; j < 8; ++j) Wsv[tid + j * 128] = Wv[tid + j * 128];
  }
#pragma unroll
  for (int j = 0; j < 16; ++j) {
    int idx = tid + j * 128;
    int n = idx >> 4;
    int c4 = (idx & 15) * 4;
    float4 v = make_float4(0.f, 0.f, 0.f, 0.f);
    if (n < nrem) v = *(const float4*)&x[(size_t)(n0 + n) * DF + c4];
    float* p = &Xs[n * 65 + c4];
    p[0] = v.x; p[1] = v.y; p[2] = v.z; p[3] = v.w;
  }
  __syncthreads();

  const int fg = (tid & 7) * 8;
  const int ng = (tid >> 3) * 8;

  float4 a0[8], a1[8];
#pragma unroll
  for (int i = 0; i < 8; ++i) {
    a0[i] = make_float4(0.f, 0.f, 0.f, 0.f);
    a1[i] = make_float4(0.f, 0.f, 0.f, 0.f);
  }

#pragma unroll 4
  for (int d = 0; d < DF; ++d) {
    float4 w0 = *(const float4*)&Ws[d * DF + fg];
    float4 w1 = *(const float4*)&Ws[d * DF + fg + 4];
#pragma unroll
    for (int i = 0; i < 8; ++i) {
      float xv = Xs[(ng + i) * 65 + d];
      a0[i].x += xv * w0.x; a0[i].y += xv * w0.y;
      a0[i].z += xv * w0.z; a0[i].w += xv * w0.w;
      a1[i].x += xv * w1.x; a1[i].y += xv * w1.y;
      a1[i].z += xv * w1.z; a1[i].w += xv * w1.w;
    }
  }

  float4 bb0 = *(const float4*)&bias[fg];
  float4 bb1 = *(const float4*)&bias[fg + 4];

#pragma unroll
  for (int i = 0; i < 8; ++i) {
    int n = ng + i;
    if (n < nrem) {
      float* op = out + (size_t)(n0 + n) * DF + fg;
      float4 o0, o1;
      if (mode == 0) {
        o0 = make_float4(a0[i].x + bb0.x, a0[i].y + bb0.y,
                         a0[i].z + bb0.z, a0[i].w + bb0.w);
        o1 = make_float4(a1[i].x + bb1.x, a1[i].y + bb1.y,
                         a1[i].z + bb1.z, a1[i].w + bb1.w);
      } else {
        o0 = *(float4*)op;
        o1 = *(float4*)(op + 4);
        o0.x += a0[i].x + bb0.x; o0.y += a0[i].y + bb0.y;
        o0.z += a0[i].z + bb0.z; o0.w += a0[i].w + bb0.w;
        o1.x += a1[i].x + bb1.x; o1.y += a1[i].y + bb1.y;
        o1.z += a1[i].z + bb1.z; o1.w += a1[i].w + bb1.w;
        if (mode == 1) {
          o0.x = fmaxf(o0.x, 0.f); o0.y = fmaxf(o0.y, 0.f);
          o0.z = fmaxf(o0.z, 0.f); o0.w = fmaxf(o0.w, 0.f);
          o1.x = fmaxf(o1.x, 0.f); o1.y = fmaxf(o1.y, 0.f);
          o1.z = fmaxf(o1.z, 0.f); o1.w = fmaxf(o1.w, 0.f);
        }
      }
      *(float4*)op = o0;
      *(float4*)(op + 4) = o1;
    }
  }
}

// ---------------------------------------------------------------------------
// CSR build: count -> hierarchical scan (3 kernels) -> fill
// ---------------------------------------------------------------------------
__global__ __launch_bounds__(256) void csr_count(
    const int* __restrict__ dst, int* __restrict__ cnt, int E)
{
  int e = blockIdx.x * 256 + threadIdx.x;
  if (e < E) atomicAdd(&cnt[dst[e]], 1);
}

// per-block sums over 2048 counts
__global__ __launch_bounds__(256) void scan_partial(
    const int* __restrict__ cnt, int* __restrict__ bsums, int N)
{
  const int t = threadIdx.x;
  const int base = blockIdx.x * 2048 + t * 8;
  int s = 0;
  if (base + 8 <= N) {
    int4 a = *(const int4*)&cnt[base];
    int4 b = *(const int4*)&cnt[base + 4];
    s = a.x + a.y + a.z + a.w + b.x + b.y + b.z + b.w;
  } else {
    for (int i = 0; i < 8; ++i) { int idx = base + i; if (idx < N) s += cnt[idx]; }
  }
  for (int off = 32; off; off >>= 1) s += __shfl_down(s, off);
  __shared__ int wt[4];
  const int lane = t & 63, wid = t >> 6;
  if (lane == 0) wt[wid] = s;
  __syncthreads();
  if (t == 0) bsums[blockIdx.x] = wt[0] + wt[1] + wt[2] + wt[3];
}

// exclusive scan of the P block sums (P small)
__global__ __launch_bounds__(64) void scan_offsets(
    int* __restrict__ bsums, int P)
{
  const int t = threadIdx.x;
  if (P <= 64) {
    int v = (t < P) ? bsums[t] : 0;
    int incl = v;
    for (int off = 1; off < 64; off <<= 1) {
      int u = __shfl_up(incl, off);
      if (t >= off) incl += u;
    }
    if (t < P) bsums[t] = incl - v;
  } else if (t == 0) {
    int run = 0;
    for (int i = 0; i < P; ++i) { int c = bsums[i]; bsums[i] = run; run += c; }
  }
}

// final: row_ptr + cursor (cursor may alias cnt: per-thread read-before-write)
__global__ __launch_bounds__(256) void scan_final(
    const int* __restrict__ cnt, const int* __restrict__ bsums,
    int* __restrict__ row_ptr, int* __restrict__ cursor, int N, int E)
{
  const int t = threadIdx.x;
  const int b = blockIdx.x;
  const int base = b * 2048 + t * 8;
  int c[8];
  if (base + 8 <= N) {
    int4 a = *(const int4*)&cnt[base];
    int4 d = *(const int4*)&cnt[base + 4];
    c[0] = a.x; c[1] = a.y; c[2] = a.z; c[3] = a.w;
    c[4] = d.x; c[5] = d.y; c[6] = d.z; c[7] = d.w;
  } else {
    for (int i = 0; i < 8; ++i) { int idx = base + i; c[i] = (idx < N) ? cnt[idx] : 0; }
  }
  int s = 0;
#pragma unroll
  for (int i = 0; i < 8; ++i) s += c[i];
  const int lane = t & 63, wid = t >> 6;
  int incl = s;
  for (int off = 1; off < 64; off <<= 1) {
    int u = __shfl_up(incl, off);
    if (lane >= off) incl += u;
  }
  __shared__ int wt[4];
  if (lane == 63) wt[wid] = incl;
  __syncthreads();
  int woff = 0;
  for (int w = 0; w < wid; ++w) woff += wt[w];
  int run = incl - s + woff + bsums[b];
#pragma unroll
  for (int i = 0; i < 8; ++i) {
    int idx = base + i;
    if (idx < N) { row_ptr[idx] = run; cursor[idx] = run; run += c[i]; }
  }
  if (b == 0 && t == 0) row_ptr[N] = E;
}

__global__ __launch_bounds__(256) void csr_fill(
    const int* __restrict__ src, const int* __restrict__ dst,
    const int* __restrict__ et, int* __restrict__ cursor,
    unsigned int* __restrict__ sorted, int E)
{
  int e = blockIdx.x * 256 + threadIdx.x;
  if (e >= E) return;
  int d = dst[e];
  int pos = atomicAdd(&cursor[d], 1);
  sorted[pos] = (unsigned int)src[e] | ((unsigned int)et[e] << 24);
}

// ---------------------------------------------------------------------------
// gather (bf16 h): out[n][:] += sum_{in-edges} h[rel][src][:]  (no atomics)
// 16 lanes per node, 4 bf16 (8B) per lane
// ---------------------------------------------------------------------------
__global__ __launch_bounds__(256) void rgcn_gather(
    const unsigned int* __restrict__ sorted,
    const int* __restrict__ row_ptr,
    const unsigned short* __restrict__ hb,  // [8, N, 64] bf16
    float* __restrict__ out,                // [N, 64]
    int N, int do_relu)
{
  const int t = threadIdx.x;
  const int node = blockIdx.x * 16 + (t >> 4);
  if (node >= N) return;
  const int l4 = (t & 15) * 4;

  int p = row_ptr[node];
  const int pe = row_ptr[node + 1];

  float4 acc = make_float4(0.f, 0.f, 0.f, 0.f);
  for (; p + 1 < pe; p += 2) {
    unsigned int pa = sorted[p];
    unsigned int pb = sorted[p + 1];
    ushort4 ua = *(const ushort4*)&hb[
        (((size_t)(pa >> 24) * N + (pa & 0xFFFFFFu)) << 6) + l4];
    ushort4 ub = *(const ushort4*)&hb[
        (((size_t)(pb >> 24) * N + (pb & 0xFFFFFFu)) << 6) + l4];
    acc.x += bf2f(ua.x) + bf2f(ub.x);
    acc.y += bf2f(ua.y) + bf2f(ub.y);
    acc.z += bf2f(ua.z) + bf2f(ub.z);
    acc.w += bf2f(ua.w) + bf2f(ub.w);
  }
  if (p < pe) {
    unsigned int pa = sorted[p];
    ushort4 ua = *(const ushort4*)&hb[
        (((size_t)(pa >> 24) * N + (pa & 0xFFFFFFu)) << 6) + l4];
    acc.x += bf2f(ua.x); acc.y += bf2f(ua.y);
    acc.z += bf2f(ua.z); acc.w += bf2f(ua.w);
  }

  float* o = out + ((size_t)node << 6) + l4;
  float4 cur = *(float4*)o;
  cur.x += acc.x; cur.y += acc.y; cur.z += acc.z; cur.w += acc.w;
  if (do_relu) {
    cur.x = fmaxf(cur.x, 0.f); cur.y = fmaxf(cur.y, 0.f);
    cur.z = fmaxf(cur.z, 0.f); cur.w = fmaxf(cur.w, 0.f);
  }
  *(float4*)o = cur;
}

// ---------------------------------------------------------------------------
// fallback atomic scatter (bf16 h) — only if ws too small for CSR path
// ---------------------------------------------------------------------------
__global__ __launch_bounds__(256) void rgcn_scatter(
    const int* __restrict__ src, const int* __restrict__ dst,
    const int* __restrict__ et,
    const unsigned short* __restrict__ hb,
    float* __restrict__ out,
    int E, int N, int r0, int r1)
{
  long long g = (long long)blockIdx.x * 256 + threadIdx.x;
  int e = (int)(g >> 4);
  if (e >= E) return;
  int r = et[e];
  if (r < r0 || r >= r1) return;
  int f4 = ((int)g & 15) * 4;
  int s = src[e];
  int d = dst[e];
  ushort4 u = *(const ushort4*)&hb[(((size_t)(r - r0) * N + s) << 6) + f4];
  float* o = out + ((size_t)d << 6) + f4;
  atomicAdd(o + 0, bf2f(u.x));
  atomicAdd(o + 1, bf2f(u.y));
  atomicAdd(o + 2, bf2f(u.z));
  atomicAdd(o + 3, bf2f(u.w));
}

// ---------------------------------------------------------------------------
extern "C" void kernel_launch(void* const* d_in, const int* in_sizes, int n_in,
                              void* d_out, int out_size, void* d_ws, size_t ws_size,
                              hipStream_t stream) {
  const int* adj    = (const int*)d_in[0];    // [2, E]
  const float* feat = (const float*)d_in[1];  // [N, 64]
  const int* et     = (const int*)d_in[2];    // [E]
  const float* W1   = (const float*)d_in[3];
  const float* rt1  = (const float*)d_in[4];
  const float* b1   = (const float*)d_in[5];
  const float* W2   = (const float*)d_in[6];
  const float* rt2  = (const float*)d_in[7];
  const float* b2   = (const float*)d_in[8];

  const int E = in_sizes[0] / 2;
  const int N = in_sizes[1] / DF;
  const int* srcp = adj;
  const int* dstp = adj + E;

  float* out = (float*)d_out;
  const size_t ND = (size_t)N * DF;
  const int nblk = (N + 127) / 128;
  const int P = (N + 2047) / 2048;   // scan blocks

  // ws layout (CSR path): hb bf16 [8,N,64] | sorted [E] | row_ptr [N+1] |
  //                       cursor [N] | bsums [P]
  const size_t need_csr = 8 * ND * sizeof(unsigned short) +
                          (size_t)E * 4 + ((size_t)N + 1) * 4 +
                          (size_t)N * 4 + (size_t)P * 4;

  if (ws_size >= need_csr) {
    unsigned short* hb = (unsigned short*)d_ws;
    unsigned int* sorted = (unsigned int*)(hb + 8 * ND);
    int* row_ptr = (int*)(sorted + E);
    int* cursor  = row_ptr + (N + 1);
    int* bsums   = cursor + N;

    // ---- build CSR once (same graph both layers) ----
    hipMemsetAsync(cursor, 0, (size_t)N * sizeof(int), stream);
    csr_count<<<(E + 255) / 256, 256, 0, stream>>>(dstp, cursor, E);
    scan_partial<<<P, 256, 0, stream>>>(cursor, bsums, N);
    scan_offsets<<<1, 64, 0, stream>>>(bsums, P);
    scan_final<<<P, 256, 0, stream>>>(cursor, bsums, row_ptr, cursor, N, E);
    csr_fill<<<(E + 255) / 256, 256, 0, stream>>>(srcp, dstp, et, cursor, sorted, E);

    const int gblk = (N + 15) / 16;

    // ---- layer 1: out = relu( gather(h1) + feat@rt1 + b1 ) ----
    // transform with ny=9: y<8 write h (bf16), y==8 writes out = feat@rt1+b1
    rgcn_transform<<<dim3(nblk, 9), 128, 0, stream>>>(feat, W1, rt1, b1, hb, out, N);
    rgcn_gather<<<gblk, 256, 0, stream>>>(sorted, row_ptr, hb, out, N, 1);

    // ---- layer 2: out = gather(h2) + out@rt2 + b2 ----
    rgcn_transform<<<dim3(nblk, 8), 128, 0, stream>>>(out, W2, nullptr, nullptr, hb, out, N);
    rgcn_root_epilogue<<<nblk, 128, 0, stream>>>(out, rt2, b2, out, N, 0);
    rgcn_gather<<<gblk, 256, 0, stream>>>(sorted, row_ptr, hb, out, N, 0);
    return;
  }

  // ---------------- fallback: atomic scatter ----------------
  size_t avail_b = ws_size;
  size_t per_rel = ND * sizeof(unsigned short);
  size_t xmid_b = ND * sizeof(float);
  int RC = 1;
  if (avail_b > per_rel + xmid_b) {
    size_t rc = (avail_b - xmid_b) / per_rel;
    RC = rc >= NREL ? NREL : (int)rc;
  }
  unsigned short* hb = (unsigned short*)d_ws;
  float* xmid = (float*)((char*)d_ws + (size_t)RC * per_rel);
  const int sblk = (int)(((size_t)E * 16 + 255) / 256);

  for (int layer = 0; layer < 2; ++layer) {
    const float* xin = layer ? xmid : feat;
    const float* W   = layer ? W2 : W1;
    const float* rt  = layer ? rt2 : rt1;
    const float* bs  = layer ? b2 : b1;
    float* o         = layer ? out : xmid;

    hipMemsetAsync(o, 0, ND * sizeof(float), stream);
    for (int r0 = 0; r0 < NREL; r0 += RC) {
      int rc = (NREL - r0) < RC ? (NREL - r0) : RC;
      rgcn_transform<<<dim3(nblk, rc), 128, 0, stream>>>(
          xin, W + (size_t)r0 * DF * DF, nullptr, nullptr, hb, nullptr, N);
      rgcn_scatter<<<sblk, 256, 0, stream>>>(
          srcp, dstp, et, hb, o, E, N, r0, r0 + rc);
    }
    rgcn_root_epilogue<<<nblk, 128, 0, stream>>>(xin, rt, bs, o, N,
                                                 layer == 0 ? 1 : 2);
  }
}

// Round 4
// 307.660 us; speedup vs baseline: 9.4738x; 1.4763x over previous
//
#include <hip/hip_runtime.h>
#include <cstdint>
#include <cstddef>

#define DF 64          // feature dim
#define NREL 8         // relations
#define DPB 128        // dst nodes per coarse bucket
#define DPB_SHIFT 7
#define NBMAX 1024     // max coarse buckets supported by LDS kernels
#define EPB 4096       // edges per binning block

// ---- bf16 helpers (RNE) ---------------------------------------------------
static __device__ __forceinline__ unsigned short f2bf(float f) {
  unsigned int u = __float_as_uint(f);
  u += 0x7FFFu + ((u >> 16) & 1u);
  return (unsigned short)(u >> 16);
}
static __device__ __forceinline__ float bf2f(unsigned short s) {
  return __uint_as_float((unsigned int)s << 16);
}

// ---------------------------------------------------------------------------
// transform: h[r][n][f] = sum_d x[n][d] * W[r][d][f]   (h stored bf16)
// blockIdx.y == 8 (when launched with ny=9): out[n][f] = x@root + bias (fp32)
// ---------------------------------------------------------------------------
__global__ __launch_bounds__(128) void rgcn_transform(
    const float* __restrict__ x,
    const float* __restrict__ Wc,
    const float* __restrict__ root,
    const float* __restrict__ bias,
    unsigned short* __restrict__ hb,
    float* __restrict__ out,
    int N)
{
  const int r = blockIdx.y;
  const bool is_root = (r == 8);
  const float* W = is_root ? root : (Wc + (size_t)r * DF * DF);

  __shared__ float Ws[DF * DF];
  __shared__ float Xs[128 * 65];

  const int tid = threadIdx.x;
  const int n0 = blockIdx.x * 128;
  const int nrem = N - n0;

  {
    const float4* Wv = (const float4*)W;
    float4* Wsv = (float4*)Ws;
#pragma unroll
    for (int j = 0; j < 8; ++j) Wsv[tid + j * 128] = Wv[tid + j * 128];
  }
#pragma unroll
  for (int j = 0; j < 16; ++j) {
    int idx = tid + j * 128;
    int n = idx >> 4;
    int c4 = (idx & 15) * 4;
    float4 v = make_float4(0.f, 0.f, 0.f, 0.f);
    if (n < nrem) v = *(const float4*)&x[(size_t)(n0 + n) * DF + c4];
    float* p = &Xs[n * 65 + c4];
    p[0] = v.x; p[1] = v.y; p[2] = v.z; p[3] = v.w;
  }
  __syncthreads();

  const int fg = (tid & 7) * 8;
  const int ng = (tid >> 3) * 8;

  float4 a0[8], a1[8];
#pragma unroll
  for (int i = 0; i < 8; ++i) {
    a0[i] = make_float4(0.f, 0.f, 0.f, 0.f);
    a1[i] = make_float4(0.f, 0.f, 0.f, 0.f);
  }

#pragma unroll 4
  for (int d = 0; d < DF; ++d) {
    float4 w0 = *(const float4*)&Ws[d * DF + fg];
    float4 w1 = *(const float4*)&Ws[d * DF + fg + 4];
#pragma unroll
    for (int i = 0; i < 8; ++i) {
      float xv = Xs[(ng + i) * 65 + d];
      a0[i].x += xv * w0.x; a0[i].y += xv * w0.y;
      a0[i].z += xv * w0.z; a0[i].w += xv * w0.w;
      a1[i].x += xv * w1.x; a1[i].y += xv * w1.y;
      a1[i].z += xv * w1.z; a1[i].w += xv * w1.w;
    }
  }

  if (is_root) {
    float4 bb0 = *(const float4*)&bias[fg];
    float4 bb1 = *(const float4*)&bias[fg + 4];
#pragma unroll
    for (int i = 0; i < 8; ++i) {
      int n = ng + i;
      if (n < nrem) {
        float* op = out + (size_t)(n0 + n) * DF + fg;
        *(float4*)op = make_float4(a0[i].x + bb0.x, a0[i].y + bb0.y,
                                   a0[i].z + bb0.z, a0[i].w + bb0.w);
        *(float4*)(op + 4) = make_float4(a1[i].x + bb1.x, a1[i].y + bb1.y,
                                         a1[i].z + bb1.z, a1[i].w + bb1.w);
      }
    }
  } else {
#pragma unroll
    for (int i = 0; i < 8; ++i) {
      int n = ng + i;
      if (n < nrem) {
        uint4 pk;
        pk.x = (unsigned)f2bf(a0[i].x) | ((unsigned)f2bf(a0[i].y) << 16);
        pk.y = (unsigned)f2bf(a0[i].z) | ((unsigned)f2bf(a0[i].w) << 16);
        pk.z = (unsigned)f2bf(a1[i].x) | ((unsigned)f2bf(a1[i].y) << 16);
        pk.w = (unsigned)f2bf(a1[i].z) | ((unsigned)f2bf(a1[i].w) << 16);
        unsigned short* op = hb + (((size_t)r * N + (n0 + n)) << 6) + fg;
        *(uint4*)op = pk;
      }
    }
  }
}

// ---------------------------------------------------------------------------
// epilogue (fp32): mode 0: out = x@root + b (overwrite)
//                  mode 1: out = relu(out + x@root + b)
//                  mode 2: out = out + x@root + b
// ---------------------------------------------------------------------------
__global__ __launch_bounds__(128) void rgcn_root_epilogue(
    const float* __restrict__ x,
    const float* __restrict__ root,
    const float* __restrict__ bias,
    float* __restrict__ out, int N, int mode)
{
  __shared__ float Ws[DF * DF];
  __shared__ float Xs[128 * 65];

  const int tid = threadIdx.x;
  const int n0 = blockIdx.x * 128;
  const int nrem = N - n0;

  {
    const float4* Wv = (const float4*)root;
    float4* Wsv = (float4*)Ws;
#pragma unroll
    for (int j = 0; j < 8; ++j) Wsv[tid + j * 128] = Wv[tid + j * 128];
  }
#pragma unroll
  for (int j = 0; j < 16; ++j) {
    int idx = tid + j * 128;
    int n = idx >> 4;
    int c4 = (idx & 15) * 4;
    float4 v = make_float4(0.f, 0.f, 0.f, 0.f);
    if (n < nrem) v = *(const float4*)&x[(size_t)(n0 + n) * DF + c4];
    float* p = &Xs[n * 65 + c4];
    p[0] = v.x; p[1] = v.y; p[2] = v.z; p[3] = v.w;
  }
  __syncthreads();

  const int fg = (tid & 7) * 8;
  const int ng = (tid >> 3) * 8;

  float4 a0[8], a1[8];
#pragma unroll
  for (int i = 0; i < 8; ++i) {
    a0[i] = make_float4(0.f, 0.f, 0.f, 0.f);
    a1[i] = make_float4(0.f, 0.f, 0.f, 0.f);
  }

#pragma unroll 4
  for (int d = 0; d < DF; ++d) {
    float4 w0 = *(const float4*)&Ws[d * DF + fg];
    float4 w1 = *(const float4*)&Ws[d * DF + fg + 4];
#pragma unroll
    for (int i = 0; i < 8; ++i) {
      float xv = Xs[(ng + i) * 65 + d];
      a0[i].x += xv * w0.x; a0[i].y += xv * w0.y;
      a0[i].z += xv * w0.z; a0[i].w += xv * w0.w;
      a1[i].x += xv * w1.x; a1[i].y += xv * w1.y;
      a1[i].z += xv * w1.z; a1[i].w += xv * w1.w;
    }
  }

  float4 bb0 = *(const float4*)&bias[fg];
  float4 bb1 = *(const float4*)&bias[fg + 4];

#pragma unroll
  for (int i = 0; i < 8; ++i) {
    int n = ng + i;
    if (n < nrem) {
      float* op = out + (size_t)(n0 + n) * DF + fg;
      float4 o0, o1;
      if (mode == 0) {
        o0 = make_float4(a0[i].x + bb0.x, a0[i].y + bb0.y,
                         a0[i].z + bb0.z, a0[i].w + bb0.w);
        o1 = make_float4(a1[i].x + bb1.x, a1[i].y + bb1.y,
                         a1[i].z + bb1.z, a1[i].w + bb1.w);
      } else {
        o0 = *(float4*)op;
        o1 = *(float4*)(op + 4);
        o0.x += a0[i].x + bb0.x; o0.y += a0[i].y + bb0.y;
        o0.z += a0[i].z + bb0.z; o0.w += a0[i].w + bb0.w;
        o1.x += a1[i].x + bb1.x; o1.y += a1[i].y + bb1.y;
        o1.z += a1[i].z + bb1.z; o1.w += a1[i].w + bb1.w;
        if (mode == 1) {
          o0.x = fmaxf(o0.x, 0.f); o0.y = fmaxf(o0.y, 0.f);
          o0.z = fmaxf(o0.z, 0.f); o0.w = fmaxf(o0.w, 0.f);
          o1.x = fmaxf(o1.x, 0.f); o1.y = fmaxf(o1.y, 0.f);
          o1.z = fmaxf(o1.z, 0.f); o1.w = fmaxf(o1.w, 0.f);
        }
      }
      *(float4*)op = o0;
      *(float4*)(op + 4) = o1;
    }
  }
}

// ---------------------------------------------------------------------------
// CSR build via two-level bucket sort
// ---------------------------------------------------------------------------
// phase 1: per-bucket edge counts (LDS histogram, few global atomics)
__global__ __launch_bounds__(256) void bucket_count(
    const int* __restrict__ dst, int* __restrict__ bcnt, int E, int NB)
{
  __shared__ int lh[NBMAX];
  const int t = threadIdx.x;
  for (int i = t; i < NB; i += 256) lh[i] = 0;
  __syncthreads();
  const int base = blockIdx.x * EPB;
  const int cnt = min(EPB, E - base);
  for (int k = t; k < cnt; k += 256)
    atomicAdd(&lh[dst[base + k] >> DPB_SHIFT], 1);
  __syncthreads();
  for (int i = t; i < NB; i += 256) {
    int c = lh[i];
    if (c) atomicAdd(&bcnt[i], c);
  }
}

// phase 2: exclusive scan of bucket counts (NB <= 1024), init cursors
__global__ __launch_bounds__(1024) void scan_buckets(
    const int* __restrict__ bcnt, int* __restrict__ boff,
    int* __restrict__ bcur, int NB, int E)
{
  __shared__ int sc[1024];
  const int t = threadIdx.x;
  int v = (t < NB) ? bcnt[t] : 0;
  sc[t] = v;
  __syncthreads();
  for (int off = 1; off < 1024; off <<= 1) {
    int u = (t >= off) ? sc[t - off] : 0;
    __syncthreads();
    sc[t] += u;
    __syncthreads();
  }
  if (t < NB) {
    int ex = sc[t] - v;
    boff[t] = ex;
    bcur[t] = ex;
  }
  if (t == 0) boff[NB] = E;
}

// phase 3: bin edges into bucket-major records; each block reserves
// contiguous runs per bucket so its writes are block-local (XCD-local)
__global__ __launch_bounds__(256) void bin_scatter(
    const int* __restrict__ src, const int* __restrict__ dst,
    const int* __restrict__ et, int* __restrict__ bcur,
    uint2* __restrict__ binned, int E, int NB)
{
  __shared__ int lh[NBMAX];     // histogram, then cursor
  const int t = threadIdx.x;
  for (int i = t; i < NB; i += 256) lh[i] = 0;
  __syncthreads();
  const int base = blockIdx.x * EPB;
  const int cnt = min(EPB, E - base);
  for (int k = t; k < cnt; k += 256)
    atomicAdd(&lh[dst[base + k] >> DPB_SHIFT], 1);
  __syncthreads();
  for (int i = t; i < NB; i += 256) {
    int c = lh[i];
    lh[i] = c ? atomicAdd(&bcur[i], c) : 0;   // reserve run, lh -> cursor
  }
  __syncthreads();
  for (int k = t; k < cnt; k += 256) {
    int e = base + k;
    int d = dst[e];
    int pos = atomicAdd(&lh[d >> DPB_SHIFT], 1);
    binned[pos] = make_uint2((unsigned)d,
                             (unsigned)src[e] | ((unsigned)et[e] << 16));
  }
}

// phase 4: per-bucket local count/scan/scatter -> row_ptr + sorted payloads
__global__ __launch_bounds__(256) void fill_bucket(
    const uint2* __restrict__ binned, const int* __restrict__ boff,
    int* __restrict__ row_ptr, unsigned int* __restrict__ sorted,
    int N, int E)
{
  __shared__ int h[DPB];
  __shared__ int sc[DPB];
  __shared__ int cur[DPB];
  const int t = threadIdx.x;
  const int b = blockIdx.x;
  const int beg = boff[b], end = boff[b + 1];
  const int dbase = b << DPB_SHIFT;

  if (t < DPB) h[t] = 0;
  __syncthreads();
  for (int k = beg + t; k < end; k += 256)
    atomicAdd(&h[binned[k].x - dbase], 1);
  __syncthreads();
  if (t < DPB) sc[t] = h[t];
  __syncthreads();
  for (int off = 1; off < DPB; off <<= 1) {
    int u = (t < DPB && t >= off) ? sc[t - off] : 0;
    __syncthreads();
    if (t < DPB) sc[t] += u;
    __syncthreads();
  }
  if (t < DPB) {
    int ex = sc[t] - h[t];
    cur[t] = ex;
    int d = dbase + t;
    if (d < N) row_ptr[d] = beg + ex;
  }
  if (b == 0 && t == 0) row_ptr[N] = E;
  __syncthreads();
  for (int k = beg + t; k < end; k += 256) {
    uint2 r = binned[k];
    int pos = beg + atomicAdd(&cur[r.x - dbase], 1);
    sorted[pos] = r.y;
  }
}

// ---------------------------------------------------------------------------
// gather (bf16 h): out[n][:] (+relu) += sum_{in-edges} h[rel][src][:]
// 8 lanes per node, 16B (8 bf16) per lane, 2-edge unroll, no atomics.
// payload: src | (rel << 16)
// ---------------------------------------------------------------------------
__global__ __launch_bounds__(256) void rgcn_gather(
    const unsigned int* __restrict__ sorted,
    const int* __restrict__ row_ptr,
    const unsigned short* __restrict__ hb,
    float* __restrict__ out,
    int N, int do_relu)
{
  const int t = threadIdx.x;
  const int node = blockIdx.x * 32 + (t >> 3);
  if (node >= N) return;
  const int l8 = (t & 7) * 8;

  int p = row_ptr[node];
  const int pe = row_ptr[node + 1];

  float acc[8];
#pragma unroll
  for (int i = 0; i < 8; ++i) acc[i] = 0.f;

  for (; p + 1 < pe; p += 2) {
    unsigned pa = sorted[p], pb = sorted[p + 1];
    uint4 ua = *(const uint4*)&hb[
        (((size_t)(pa >> 16) * N + (pa & 0xFFFFu)) << 6) + l8];
    uint4 ub = *(const uint4*)&hb[
        (((size_t)(pb >> 16) * N + (pb & 0xFFFFu)) << 6) + l8];
    acc[0] += bf2f((unsigned short)ua.x) + bf2f((unsigned short)ub.x);
    acc[1] += bf2f((unsigned short)(ua.x >> 16)) + bf2f((unsigned short)(ub.x >> 16));
    acc[2] += bf2f((unsigned short)ua.y) + bf2f((unsigned short)ub.y);
    acc[3] += bf2f((unsigned short)(ua.y >> 16)) + bf2f((unsigned short)(ub.y >> 16));
    acc[4] += bf2f((unsigned short)ua.z) + bf2f((unsigned short)ub.z);
    acc[5] += bf2f((unsigned short)(ua.z >> 16)) + bf2f((unsigned short)(ub.z >> 16));
    acc[6] += bf2f((unsigned short)ua.w) + bf2f((unsigned short)ub.w);
    acc[7] += bf2f((unsigned short)(ua.w >> 16)) + bf2f((unsigned short)(ub.w >> 16));
  }
  if (p < pe) {
    unsigned pa = sorted[p];
    uint4 ua = *(const uint4*)&hb[
        (((size_t)(pa >> 16) * N + (pa & 0xFFFFu)) << 6) + l8];
    acc[0] += bf2f((unsigned short)ua.x);
    acc[1] += bf2f((unsigned short)(ua.x >> 16));
    acc[2] += bf2f((unsigned short)ua.y);
    acc[3] += bf2f((unsigned short)(ua.y >> 16));
    acc[4] += bf2f((unsigned short)ua.z);
    acc[5] += bf2f((unsigned short)(ua.z >> 16));
    acc[6] += bf2f((unsigned short)ua.w);
    acc[7] += bf2f((unsigned short)(ua.w >> 16));
  }

  float* o = out + ((size_t)node << 6) + l8;
  float4 c0 = *(float4*)o;
  float4 c1 = *(float4*)(o + 4);
  c0.x += acc[0]; c0.y += acc[1]; c0.z += acc[2]; c0.w += acc[3];
  c1.x += acc[4]; c1.y += acc[5]; c1.z += acc[6]; c1.w += acc[7];
  if (do_relu) {
    c0.x = fmaxf(c0.x, 0.f); c0.y = fmaxf(c0.y, 0.f);
    c0.z = fmaxf(c0.z, 0.f); c0.w = fmaxf(c0.w, 0.f);
    c1.x = fmaxf(c1.x, 0.f); c1.y = fmaxf(c1.y, 0.f);
    c1.z = fmaxf(c1.z, 0.f); c1.w = fmaxf(c1.w, 0.f);
  }
  *(float4*)o = c0;
  *(float4*)(o + 4) = c1;
}

// ---------------------------------------------------------------------------
// fallback atomic scatter (bf16 h) — only if ws too small for CSR path
// ---------------------------------------------------------------------------
__global__ __launch_bounds__(256) void rgcn_scatter(
    const int* __restrict__ src, const int* __restrict__ dst,
    const int* __restrict__ et,
    const unsigned short* __restrict__ hb,
    float* __restrict__ out,
    int E, int N, int r0, int r1)
{
  long long g = (long long)blockIdx.x * 256 + threadIdx.x;
  int e = (int)(g >> 4);
  if (e >= E) return;
  int r = et[e];
  if (r < r0 || r >= r1) return;
  int f4 = ((int)g & 15) * 4;
  int s = src[e];
  int d = dst[e];
  ushort4 u = *(const ushort4*)&hb[(((size_t)(r - r0) * N + s) << 6) + f4];
  float* o = out + ((size_t)d << 6) + f4;
  atomicAdd(o + 0, bf2f(u.x));
  atomicAdd(o + 1, bf2f(u.y));
  atomicAdd(o + 2, bf2f(u.z));
  atomicAdd(o + 3, bf2f(u.w));
}

// ---------------------------------------------------------------------------
extern "C" void kernel_launch(void* const* d_in, const int* in_sizes, int n_in,
                              void* d_out, int out_size, void* d_ws, size_t ws_size,
                              hipStream_t stream) {
  const int* adj    = (const int*)d_in[0];    // [2, E]
  const float* feat = (const float*)d_in[1];  // [N, 64]
  const int* et     = (const int*)d_in[2];    // [E]
  const float* W1   = (const float*)d_in[3];
  const float* rt1  = (const float*)d_in[4];
  const float* b1   = (const float*)d_in[5];
  const float* W2   = (const float*)d_in[6];
  const float* rt2  = (const float*)d_in[7];
  const float* b2   = (const float*)d_in[8];

  const int E = in_sizes[0] / 2;
  const int N = in_sizes[1] / DF;
  const int* srcp = adj;
  const int* dstp = adj + E;

  float* out = (float*)d_out;
  const size_t ND = (size_t)N * DF;
  const int nblk = (N + 127) / 128;
  const int NB = (N + DPB - 1) >> DPB_SHIFT;

  // ws layout (CSR path): hb bf16 [8,N,64] | binned uint2[E] | sorted uint[E]
  //                       | row_ptr int[N+1] | bcnt[NB] | boff[NB+1] | bcur[NB]
  const size_t need_csr = 8 * ND * sizeof(unsigned short) +
                          (size_t)E * 8 + (size_t)E * 4 +
                          ((size_t)N + 1) * 4 + ((size_t)3 * NB + 1) * 4;

  if (ws_size >= need_csr && NB <= NBMAX && N < 65536) {
    unsigned short* hb = (unsigned short*)d_ws;
    uint2* binned = (uint2*)(hb + 8 * ND);
    unsigned int* sorted = (unsigned int*)(binned + E);
    int* row_ptr = (int*)(sorted + E);
    int* bcnt = row_ptr + (N + 1);
    int* boff = bcnt + NB;
    int* bcur = boff + (NB + 1);

    // ---- build CSR once (same graph both layers) ----
    const int ebk = (E + EPB - 1) / EPB;
    hipMemsetAsync(bcnt, 0, (size_t)NB * sizeof(int), stream);
    bucket_count<<<ebk, 256, 0, stream>>>(dstp, bcnt, E, NB);
    scan_buckets<<<1, 1024, 0, stream>>>(bcnt, boff, bcur, NB, E);
    bin_scatter<<<ebk, 256, 0, stream>>>(srcp, dstp, et, bcur, binned, E, NB);
    fill_bucket<<<NB, 256, 0, stream>>>(binned, boff, row_ptr, sorted, N, E);

    const int gblk = (N + 31) / 32;

    // ---- layer 1: out = relu( gather(h1) + feat@rt1 + b1 ) ----
    rgcn_transform<<<dim3(nblk, 9), 128, 0, stream>>>(feat, W1, rt1, b1, hb, out, N);
    rgcn_gather<<<gblk, 256, 0, stream>>>(sorted, row_ptr, hb, out, N, 1);

    // ---- layer 2: out = gather(h2) + out@rt2 + b2 ----
    rgcn_transform<<<dim3(nblk, 8), 128, 0, stream>>>(out, W2, nullptr, nullptr, hb, out, N);
    rgcn_root_epilogue<<<nblk, 128, 0, stream>>>(out, rt2, b2, out, N, 0);
    rgcn_gather<<<gblk, 256, 0, stream>>>(sorted, row_ptr, hb, out, N, 0);
    return;
  }

  // ---------------- fallback: atomic scatter ----------------
  size_t per_rel = ND * sizeof(unsigned short);
  size_t xmid_b = ND * sizeof(float);
  int RC = 1;
  if (ws_size > per_rel + xmid_b) {
    size_t rc = (ws_size - xmid_b) / per_rel;
    RC = rc >= NREL ? NREL : (int)rc;
  }
  unsigned short* hb = (unsigned short*)d_ws;
  float* xmid = (float*)((char*)d_ws + (size_t)RC * per_rel);
  const int sblk = (int)(((size_t)E * 16 + 255) / 256);

  for (int layer = 0; layer < 2; ++layer) {
    const float* xin = layer ? xmid : feat;
    const float* W   = layer ? W2 : W1;
    const float* rt  = layer ? rt2 : rt1;
    const float* bs  = layer ? b2 : b1;
    float* o         = layer ? out : xmid;

    hipMemsetAsync(o, 0, ND * sizeof(float), stream);
    for (int r0 = 0; r0 < NREL; r0 += RC) {
      int rc = (NREL - r0) < RC ? (NREL - r0) : RC;
      rgcn_transform<<<dim3(nblk, rc), 128, 0, stream>>>(
          xin, W + (size_t)r0 * DF * DF, nullptr, nullptr, hb, nullptr, N);
      rgcn_scatter<<<sblk, 256, 0, stream>>>(
          srcp, dstp, et, hb, o, E, N, r0, r0 + rc);
    }
    rgcn_root_epilogue<<<nblk, 128, 0, stream>>>(xin, rt, bs, o, N,
                                                 layer == 0 ? 1 : 2);
  }
}

// Round 5
// 223.407 us; speedup vs baseline: 13.0466x; 1.3771x over previous
//
#include <hip/hip_runtime.h>
#include <cstdint>
#include <cstddef>

#define DF 64          // feature dim
#define NREL 8         // relations
#define DPB 128        // dst nodes per coarse bucket
#define DPB_SHIFT 7
#define NBMAX 1024     // max coarse buckets supported by LDS kernels
#define EPB 4096       // edges per binning block

typedef __attribute__((ext_vector_type(8))) short bf16x8;
typedef __attribute__((ext_vector_type(4))) float f32x4;

// ---- bf16 helpers (RNE) ---------------------------------------------------
static __device__ __forceinline__ unsigned short f2bf(float f) {
  unsigned int u = __float_as_uint(f);
  u += 0x7FFFu + ((u >> 16) & 1u);
  return (unsigned short)(u >> 16);
}
static __device__ __forceinline__ float bf2f(unsigned short s) {
  return __uint_as_float((unsigned int)s << 16);
}

// ---------------------------------------------------------------------------
// fp32 -> bf16 bulk convert (8 elems/thread)
// ---------------------------------------------------------------------------
__global__ __launch_bounds__(256) void to_bf16(
    const float* __restrict__ x, unsigned short* __restrict__ xb, int n8)
{
  int i = blockIdx.x * 256 + threadIdx.x;
  if (i >= n8) return;
  const float4 v0 = *(const float4*)&x[(size_t)i * 8];
  const float4 v1 = *(const float4*)&x[(size_t)i * 8 + 4];
  uint4 pk;
  pk.x = (unsigned)f2bf(v0.x) | ((unsigned)f2bf(v0.y) << 16);
  pk.y = (unsigned)f2bf(v0.z) | ((unsigned)f2bf(v0.w) << 16);
  pk.z = (unsigned)f2bf(v1.x) | ((unsigned)f2bf(v1.y) << 16);
  pk.w = (unsigned)f2bf(v1.z) | ((unsigned)f2bf(v1.w) << 16);
  *(uint4*)&xb[(size_t)i * 8] = pk;
}

// ---------------------------------------------------------------------------
// pack W (fp32 [64][64]) into bf16 MFMA B-fragments.
// frag[((mat*4 + nt)*2 + ks)*64 + l] = { W[ks*32 + (l>>4)*8 + j][nt*16 + (l&15)] }
// mats 0..7 = W1 relations, 8..15 = W2 relations.
// ---------------------------------------------------------------------------
__global__ __launch_bounds__(512) void pack_wfrag(
    const float* __restrict__ W1, const float* __restrict__ W2,
    bf16x8* __restrict__ frag)
{
  const int mat = blockIdx.x;    // 0..15
  const float* W = (mat < 8) ? (W1 + (size_t)mat * 4096)
                             : (W2 + (size_t)(mat - 8) * 4096);
  const int idx = threadIdx.x;   // 0..511
  const int nt = idx >> 7;
  const int ks = (idx >> 6) & 1;
  const int l  = idx & 63;
  const int col = nt * 16 + (l & 15);
  const int k0  = ks * 32 + (l >> 4) * 8;
  bf16x8 f;
#pragma unroll
  for (int j = 0; j < 8; ++j)
    f[j] = (short)f2bf(W[(size_t)(k0 + j) * 64 + col]);
  frag[(((size_t)mat * 4 + nt) * 2 + ks) * 64 + l] = f;
}

// ---------------------------------------------------------------------------
// MFMA transform: h[r][n][f] = sum_d xb[n][d] * W[r][d][f]  (bf16 in, bf16 out)
// block = 256 thr = 4 waves; block tile = 128 nodes; wave tile = 32 nodes x 64 f.
// A-fragments loaded once per wave; loop over 8 relations loads only W frags.
// ---------------------------------------------------------------------------
__global__ __launch_bounds__(256) void mfma_transform(
    const unsigned short* __restrict__ xb,   // [N][64] bf16
    const bf16x8* __restrict__ wfrag,        // [8][4][2][64]
    unsigned short* __restrict__ hb,         // [8][N][64] bf16
    int N)
{
  const int tid = threadIdx.x;
  const int l  = tid & 63;
  const int w  = tid >> 6;
  const int n0 = blockIdx.x * 128 + w * 32;
  const int lr = l & 15;   // A row / B col within 16-tile
  const int lg = l >> 4;   // k-group

  bf16x8 a[2][2];
#pragma unroll
  for (int mt = 0; mt < 2; ++mt) {
    const int row = n0 + mt * 16 + lr;
#pragma unroll
    for (int ks = 0; ks < 2; ++ks) {
      if (row < N)
        a[mt][ks] = *(const bf16x8*)&xb[(size_t)row * 64 + ks * 32 + lg * 8];
      else
        a[mt][ks] = (bf16x8)(short)0;
    }
  }

  for (int r = 0; r < NREL; ++r) {
    const bf16x8* wf = wfrag + (size_t)r * 8 * 64;
    bf16x8 b[4][2];
#pragma unroll
    for (int nt = 0; nt < 4; ++nt)
#pragma unroll
      for (int ks = 0; ks < 2; ++ks)
        b[nt][ks] = wf[(nt * 2 + ks) * 64 + l];

    f32x4 acc[2][4];
#pragma unroll
    for (int mt = 0; mt < 2; ++mt)
#pragma unroll
      for (int nt = 0; nt < 4; ++nt)
        acc[mt][nt] = (f32x4)(0.f);

#pragma unroll
    for (int ks = 0; ks < 2; ++ks)
#pragma unroll
      for (int mt = 0; mt < 2; ++mt)
#pragma unroll
        for (int nt = 0; nt < 4; ++nt)
          acc[mt][nt] = __builtin_amdgcn_mfma_f32_16x16x32_bf16(
              a[mt][ks], b[nt][ks], acc[mt][nt], 0, 0, 0);

    unsigned short* hr = hb + (size_t)r * N * 64;
#pragma unroll
    for (int mt = 0; mt < 2; ++mt) {
#pragma unroll
      for (int i = 0; i < 4; ++i) {
        const int node = n0 + mt * 16 + lg * 4 + i;
        if (node < N) {
          unsigned short* o = hr + (size_t)node * 64 + lr;
#pragma unroll
          for (int nt = 0; nt < 4; ++nt)
            o[nt * 16] = f2bf(acc[mt][nt][i]);
        }
      }
    }
  }
}

// ---------------------------------------------------------------------------
// fp32 vector transform (FALLBACK path only): h bf16, optional fused root
// ---------------------------------------------------------------------------
__global__ __launch_bounds__(128) void rgcn_transform(
    const float* __restrict__ x,
    const float* __restrict__ Wc,
    const float* __restrict__ root,
    const float* __restrict__ bias,
    unsigned short* __restrict__ hb,
    float* __restrict__ out,
    int N)
{
  const int r = blockIdx.y;
  const bool is_root = (r == 8);
  const float* W = is_root ? root : (Wc + (size_t)r * DF * DF);

  __shared__ float Ws[DF * DF];
  __shared__ float Xs[128 * 65];

  const int tid = threadIdx.x;
  const int n0 = blockIdx.x * 128;
  const int nrem = N - n0;

  {
    const float4* Wv = (const float4*)W;
    float4* Wsv = (float4*)Ws;
#pragma unroll
    for (int j = 0; j < 8; ++j) Wsv[tid + j * 128] = Wv[tid + j * 128];
  }
#pragma unroll
  for (int j = 0; j < 16; ++j) {
    int idx = tid + j * 128;
    int n = idx >> 4;
    int c4 = (idx & 15) * 4;
    float4 v = make_float4(0.f, 0.f, 0.f, 0.f);
    if (n < nrem) v = *(const float4*)&x[(size_t)(n0 + n) * DF + c4];
    float* p = &Xs[n * 65 + c4];
    p[0] = v.x; p[1] = v.y; p[2] = v.z; p[3] = v.w;
  }
  __syncthreads();

  const int fg = (tid & 7) * 8;
  const int ng = (tid >> 3) * 8;

  float4 a0[8], a1[8];
#pragma unroll
  for (int i = 0; i < 8; ++i) {
    a0[i] = make_float4(0.f, 0.f, 0.f, 0.f);
    a1[i] = make_float4(0.f, 0.f, 0.f, 0.f);
  }

#pragma unroll 4
  for (int d = 0; d < DF; ++d) {
    float4 w0 = *(const float4*)&Ws[d * DF + fg];
    float4 w1 = *(const float4*)&Ws[d * DF + fg + 4];
#pragma unroll
    for (int i = 0; i < 8; ++i) {
      float xv = Xs[(ng + i) * 65 + d];
      a0[i].x += xv * w0.x; a0[i].y += xv * w0.y;
      a0[i].z += xv * w0.z; a0[i].w += xv * w0.w;
      a1[i].x += xv * w1.x; a1[i].y += xv * w1.y;
      a1[i].z += xv * w1.z; a1[i].w += xv * w1.w;
    }
  }

  if (is_root) {
    float4 bb0 = *(const float4*)&bias[fg];
    float4 bb1 = *(const float4*)&bias[fg + 4];
#pragma unroll
    for (int i = 0; i < 8; ++i) {
      int n = ng + i;
      if (n < nrem) {
        float* op = out + (size_t)(n0 + n) * DF + fg;
        *(float4*)op = make_float4(a0[i].x + bb0.x, a0[i].y + bb0.y,
                                   a0[i].z + bb0.z, a0[i].w + bb0.w);
        *(float4*)(op + 4) = make_float4(a1[i].x + bb1.x, a1[i].y + bb1.y,
                                         a1[i].z + bb1.z, a1[i].w + bb1.w);
      }
    }
  } else {
#pragma unroll
    for (int i = 0; i < 8; ++i) {
      int n = ng + i;
      if (n < nrem) {
        uint4 pk;
        pk.x = (unsigned)f2bf(a0[i].x) | ((unsigned)f2bf(a0[i].y) << 16);
        pk.y = (unsigned)f2bf(a0[i].z) | ((unsigned)f2bf(a0[i].w) << 16);
        pk.z = (unsigned)f2bf(a1[i].x) | ((unsigned)f2bf(a1[i].y) << 16);
        pk.w = (unsigned)f2bf(a1[i].z) | ((unsigned)f2bf(a1[i].w) << 16);
        unsigned short* op = hb + (((size_t)r * N + (n0 + n)) << 6) + fg;
        *(uint4*)op = pk;
      }
    }
  }
}

// ---------------------------------------------------------------------------
// epilogue (fp32): mode 0: out = x@root + b (overwrite)
//                  mode 1: out = relu(out + x@root + b)
//                  mode 2: out = out + x@root + b
// ---------------------------------------------------------------------------
__global__ __launch_bounds__(128) void rgcn_root_epilogue(
    const float* __restrict__ x,
    const float* __restrict__ root,
    const float* __restrict__ bias,
    float* __restrict__ out, int N, int mode)
{
  __shared__ float Ws[DF * DF];
  __shared__ float Xs[128 * 65];

  const int tid = threadIdx.x;
  const int n0 = blockIdx.x * 128;
  const int nrem = N - n0;

  {
    const float4* Wv = (const float4*)root;
    float4* Wsv = (float4*)Ws;
#pragma unroll
    for (int j = 0; j < 8; ++j) Wsv[tid + j * 128] = Wv[tid + j * 128];
  }
#pragma unroll
  for (int j = 0; j < 16; ++j) {
    int idx = tid + j * 128;
    int n = idx >> 4;
    int c4 = (idx & 15) * 4;
    float4 v = make_float4(0.f, 0.f, 0.f, 0.f);
    if (n < nrem) v = *(const float4*)&x[(size_t)(n0 + n) * DF + c4];
    float* p = &Xs[n * 65 + c4];
    p[0] = v.x; p[1] = v.y; p[2] = v.z; p[3] = v.w;
  }
  __syncthreads();

  const int fg = (tid & 7) * 8;
  const int ng = (tid >> 3) * 8;

  float4 a0[8], a1[8];
#pragma unroll
  for (int i = 0; i < 8; ++i) {
    a0[i] = make_float4(0.f, 0.f, 0.f, 0.f);
    a1[i] = make_float4(0.f, 0.f, 0.f, 0.f);
  }

#pragma unroll 4
  for (int d = 0; d < DF; ++d) {
    float4 w0 = *(const float4*)&Ws[d * DF + fg];
    float4 w1 = *(const float4*)&Ws[d * DF + fg + 4];
#pragma unroll
    for (int i = 0; i < 8; ++i) {
      float xv = Xs[(ng + i) * 65 + d];
      a0[i].x += xv * w0.x; a0[i].y += xv * w0.y;
      a0[i].z += xv * w0.z; a0[i].w += xv * w0.w;
      a1[i].x += xv * w1.x; a1[i].y += xv * w1.y;
      a1[i].z += xv * w1.z; a1[i].w += xv * w1.w;
    }
  }

  float4 bb0 = *(const float4*)&bias[fg];
  float4 bb1 = *(const float4*)&bias[fg + 4];

#pragma unroll
  for (int i = 0; i < 8; ++i) {
    int n = ng + i;
    if (n < nrem) {
      float* op = out + (size_t)(n0 + n) * DF + fg;
      float4 o0, o1;
      if (mode == 0) {
        o0 = make_float4(a0[i].x + bb0.x, a0[i].y + bb0.y,
                         a0[i].z + bb0.z, a0[i].w + bb0.w);
        o1 = make_float4(a1[i].x + bb1.x, a1[i].y + bb1.y,
                         a1[i].z + bb1.z, a1[i].w + bb1.w);
      } else {
        o0 = *(float4*)op;
        o1 = *(float4*)(op + 4);
        o0.x += a0[i].x + bb0.x; o0.y += a0[i].y + bb0.y;
        o0.z += a0[i].z + bb0.z; o0.w += a0[i].w + bb0.w;
        o1.x += a1[i].x + bb1.x; o1.y += a1[i].y + bb1.y;
        o1.z += a1[i].z + bb1.z; o1.w += a1[i].w + bb1.w;
        if (mode == 1) {
          o0.x = fmaxf(o0.x, 0.f); o0.y = fmaxf(o0.y, 0.f);
          o0.z = fmaxf(o0.z, 0.f); o0.w = fmaxf(o0.w, 0.f);
          o1.x = fmaxf(o1.x, 0.f); o1.y = fmaxf(o1.y, 0.f);
          o1.z = fmaxf(o1.z, 0.f); o1.w = fmaxf(o1.w, 0.f);
        }
      }
      *(float4*)op = o0;
      *(float4*)(op + 4) = o1;
    }
  }
}

// ---------------------------------------------------------------------------
// CSR build via two-level bucket sort
// ---------------------------------------------------------------------------
__global__ __launch_bounds__(256) void bucket_count(
    const int* __restrict__ dst, int* __restrict__ bcnt, int E, int NB)
{
  __shared__ int lh[NBMAX];
  const int t = threadIdx.x;
  for (int i = t; i < NB; i += 256) lh[i] = 0;
  __syncthreads();
  const int base = blockIdx.x * EPB;
  const int cnt = min(EPB, E - base);
  for (int k = t; k < cnt; k += 256)
    atomicAdd(&lh[dst[base + k] >> DPB_SHIFT], 1);
  __syncthreads();
  for (int i = t; i < NB; i += 256) {
    int c = lh[i];
    if (c) atomicAdd(&bcnt[i], c);
  }
}

__global__ __launch_bounds__(1024) void scan_buckets(
    const int* __restrict__ bcnt, int* __restrict__ boff,
    int* __restrict__ bcur, int NB, int E)
{
  __shared__ int sc[1024];
  const int t = threadIdx.x;
  int v = (t < NB) ? bcnt[t] : 0;
  sc[t] = v;
  __syncthreads();
  for (int off = 1; off < 1024; off <<= 1) {
    int u = (t >= off) ? sc[t - off] : 0;
    __syncthreads();
    sc[t] += u;
    __syncthreads();
  }
  if (t < NB) {
    int ex = sc[t] - v;
    boff[t] = ex;
    bcur[t] = ex;
  }
  if (t == 0) boff[NB] = E;
}

__global__ __launch_bounds__(256) void bin_scatter(
    const int* __restrict__ src, const int* __restrict__ dst,
    const int* __restrict__ et, int* __restrict__ bcur,
    uint2* __restrict__ binned, int E, int NB)
{
  __shared__ int lh[NBMAX];
  const int t = threadIdx.x;
  for (int i = t; i < NB; i += 256) lh[i] = 0;
  __syncthreads();
  const int base = blockIdx.x * EPB;
  const int cnt = min(EPB, E - base);
  for (int k = t; k < cnt; k += 256)
    atomicAdd(&lh[dst[base + k] >> DPB_SHIFT], 1);
  __syncthreads();
  for (int i = t; i < NB; i += 256) {
    int c = lh[i];
    lh[i] = c ? atomicAdd(&bcur[i], c) : 0;
  }
  __syncthreads();
  for (int k = t; k < cnt; k += 256) {
    int e = base + k;
    int d = dst[e];
    int pos = atomicAdd(&lh[d >> DPB_SHIFT], 1);
    binned[pos] = make_uint2((unsigned)d,
                             (unsigned)src[e] | ((unsigned)et[e] << 16));
  }
}

__global__ __launch_bounds__(256) void fill_bucket(
    const uint2* __restrict__ binned, const int* __restrict__ boff,
    int* __restrict__ row_ptr, unsigned int* __restrict__ sorted,
    int N, int E)
{
  __shared__ int h[DPB];
  __shared__ int sc[DPB];
  __shared__ int cur[DPB];
  const int t = threadIdx.x;
  const int b = blockIdx.x;
  const int beg = boff[b], end = boff[b + 1];
  const int dbase = b << DPB_SHIFT;

  if (t < DPB) h[t] = 0;
  __syncthreads();
  for (int k = beg + t; k < end; k += 256)
    atomicAdd(&h[binned[k].x - dbase], 1);
  __syncthreads();
  if (t < DPB) sc[t] = h[t];
  __syncthreads();
  for (int off = 1; off < DPB; off <<= 1) {
    int u = (t < DPB && t >= off) ? sc[t - off] : 0;
    __syncthreads();
    if (t < DPB) sc[t] += u;
    __syncthreads();
  }
  if (t < DPB) {
    int ex = sc[t] - h[t];
    cur[t] = ex;
    int d = dbase + t;
    if (d < N) row_ptr[d] = beg + ex;
  }
  if (b == 0 && t == 0) row_ptr[N] = E;
  __syncthreads();
  for (int k = beg + t; k < end; k += 256) {
    uint2 r = binned[k];
    int pos = beg + atomicAdd(&cur[r.x - dbase], 1);
    sorted[pos] = r.y;
  }
}

// ---------------------------------------------------------------------------
// gather (bf16 h): out[n][:] (+relu) += sum_{in-edges} h[rel][src][:]
// 8 lanes per node, 16B per lane, 2-edge unroll. payload: src | (rel << 16)
// ---------------------------------------------------------------------------
__global__ __launch_bounds__(256) void rgcn_gather(
    const unsigned int* __restrict__ sorted,
    const int* __restrict__ row_ptr,
    const unsigned short* __restrict__ hb,
    float* __restrict__ out,
    int N, int do_relu)
{
  const int t = threadIdx.x;
  const int node = blockIdx.x * 32 + (t >> 3);
  if (node >= N) return;
  const int l8 = (t & 7) * 8;

  int p = row_ptr[node];
  const int pe = row_ptr[node + 1];

  float acc[8];
#pragma unroll
  for (int i = 0; i < 8; ++i) acc[i] = 0.f;

  for (; p + 1 < pe; p += 2) {
    unsigned pa = sorted[p], pb = sorted[p + 1];
    uint4 ua = *(const uint4*)&hb[
        (((size_t)(pa >> 16) * N + (pa & 0xFFFFu)) << 6) + l8];
    uint4 ub = *(const uint4*)&hb[
        (((size_t)(pb >> 16) * N + (pb & 0xFFFFu)) << 6) + l8];
    acc[0] += bf2f((unsigned short)ua.x) + bf2f((unsigned short)ub.x);
    acc[1] += bf2f((unsigned short)(ua.x >> 16)) + bf2f((unsigned short)(ub.x >> 16));
    acc[2] += bf2f((unsigned short)ua.y) + bf2f((unsigned short)ub.y);
    acc[3] += bf2f((unsigned short)(ua.y >> 16)) + bf2f((unsigned short)(ub.y >> 16));
    acc[4] += bf2f((unsigned short)ua.z) + bf2f((unsigned short)ub.z);
    acc[5] += bf2f((unsigned short)(ua.z >> 16)) + bf2f((unsigned short)(ub.z >> 16));
    acc[6] += bf2f((unsigned short)ua.w) + bf2f((unsigned short)ub.w);
    acc[7] += bf2f((unsigned short)(ua.w >> 16)) + bf2f((unsigned short)(ub.w >> 16));
  }
  if (p < pe) {
    unsigned pa = sorted[p];
    uint4 ua = *(const uint4*)&hb[
        (((size_t)(pa >> 16) * N + (pa & 0xFFFFu)) << 6) + l8];
    acc[0] += bf2f((unsigned short)ua.x);
    acc[1] += bf2f((unsigned short)(ua.x >> 16));
    acc[2] += bf2f((unsigned short)ua.y);
    acc[3] += bf2f((unsigned short)(ua.y >> 16));
    acc[4] += bf2f((unsigned short)ua.z);
    acc[5] += bf2f((unsigned short)(ua.z >> 16));
    acc[6] += bf2f((unsigned short)ua.w);
    acc[7] += bf2f((unsigned short)(ua.w >> 16));
  }

  float* o = out + ((size_t)node << 6) + l8;
  float4 c0 = *(float4*)o;
  float4 c1 = *(float4*)(o + 4);
  c0.x += acc[0]; c0.y += acc[1]; c0.z += acc[2]; c0.w += acc[3];
  c1.x += acc[4]; c1.y += acc[5]; c1.z += acc[6]; c1.w += acc[7];
  if (do_relu) {
    c0.x = fmaxf(c0.x, 0.f); c0.y = fmaxf(c0.y, 0.f);
    c0.z = fmaxf(c0.z, 0.f); c0.w = fmaxf(c0.w, 0.f);
    c1.x = fmaxf(c1.x, 0.f); c1.y = fmaxf(c1.y, 0.f);
    c1.z = fmaxf(c1.z, 0.f); c1.w = fmaxf(c1.w, 0.f);
  }
  *(float4*)o = c0;
  *(float4*)(o + 4) = c1;
}

// ---------------------------------------------------------------------------
// fallback atomic scatter (bf16 h) — only if ws too small for CSR path
// ---------------------------------------------------------------------------
__global__ __launch_bounds__(256) void rgcn_scatter(
    const int* __restrict__ src, const int* __restrict__ dst,
    const int* __restrict__ et,
    const unsigned short* __restrict__ hb,
    float* __restrict__ out,
    int E, int N, int r0, int r1)
{
  long long g = (long long)blockIdx.x * 256 + threadIdx.x;
  int e = (int)(g >> 4);
  if (e >= E) return;
  int r = et[e];
  if (r < r0 || r >= r1) return;
  int f4 = ((int)g & 15) * 4;
  int s = src[e];
  int d = dst[e];
  ushort4 u = *(const ushort4*)&hb[(((size_t)(r - r0) * N + s) << 6) + f4];
  float* o = out + ((size_t)d << 6) + f4;
  atomicAdd(o + 0, bf2f(u.x));
  atomicAdd(o + 1, bf2f(u.y));
  atomicAdd(o + 2, bf2f(u.z));
  atomicAdd(o + 3, bf2f(u.w));
}

// ---------------------------------------------------------------------------
extern "C" void kernel_launch(void* const* d_in, const int* in_sizes, int n_in,
                              void* d_out, int out_size, void* d_ws, size_t ws_size,
                              hipStream_t stream) {
  const int* adj    = (const int*)d_in[0];    // [2, E]
  const float* feat = (const float*)d_in[1];  // [N, 64]
  const int* et     = (const int*)d_in[2];    // [E]
  const float* W1   = (const float*)d_in[3];
  const float* rt1  = (const float*)d_in[4];
  const float* b1   = (const float*)d_in[5];
  const float* W2   = (const float*)d_in[6];
  const float* rt2  = (const float*)d_in[7];
  const float* b2   = (const float*)d_in[8];

  const int E = in_sizes[0] / 2;
  const int N = in_sizes[1] / DF;
  const int* srcp = adj;
  const int* dstp = adj + E;

  float* out = (float*)d_out;
  const size_t ND = (size_t)N * DF;
  const int nblk = (N + 127) / 128;
  const int NB = (N + DPB - 1) >> DPB_SHIFT;

  // ws layout: hb bf16[8,N,64] | xb bf16[N,64] | wfrag[16*8*64 bf16x8] |
  //            binned uint2[E] | sorted uint[E] | row_ptr[N+1] | bcnt|boff|bcur
  const size_t wfrag_elems = (size_t)16 * 8 * 64;  // bf16x8 units
  const size_t need_csr = 8 * ND * 2 + ND * 2 + wfrag_elems * 16 +
                          (size_t)E * 8 + (size_t)E * 4 +
                          ((size_t)N + 1) * 4 + ((size_t)3 * NB + 1) * 4;

  if (ws_size >= need_csr && NB <= NBMAX && N < 65536 && (N * DF) % 8 == 0) {
    unsigned short* hb = (unsigned short*)d_ws;
    unsigned short* xb = hb + 8 * ND;
    bf16x8* wfrag = (bf16x8*)(xb + ND);
    uint2* binned = (uint2*)(wfrag + wfrag_elems);
    unsigned int* sorted = (unsigned int*)(binned + E);
    int* row_ptr = (int*)(sorted + E);
    int* bcnt = row_ptr + (N + 1);
    int* boff = bcnt + NB;
    int* bcur = boff + (NB + 1);

    // ---- build CSR once (same graph both layers) ----
    const int ebk = (E + EPB - 1) / EPB;
    hipMemsetAsync(bcnt, 0, (size_t)NB * sizeof(int), stream);
    bucket_count<<<ebk, 256, 0, stream>>>(dstp, bcnt, E, NB);
    scan_buckets<<<1, 1024, 0, stream>>>(bcnt, boff, bcur, NB, E);
    bin_scatter<<<ebk, 256, 0, stream>>>(srcp, dstp, et, bcur, binned, E, NB);
    fill_bucket<<<NB, 256, 0, stream>>>(binned, boff, row_ptr, sorted, N, E);

    // ---- pack weights into MFMA fragments (both layers) ----
    pack_wfrag<<<16, 512, 0, stream>>>(W1, W2, wfrag);

    const int gblk = (N + 31) / 32;
    const int cblk = ((N * DF / 8) + 255) / 256;

    // ---- layer 1: out = relu( gather(h1) + feat@rt1 + b1 ) ----
    to_bf16<<<cblk, 256, 0, stream>>>(feat, xb, N * DF / 8);
    mfma_transform<<<nblk, 256, 0, stream>>>(xb, wfrag, hb, N);
    rgcn_root_epilogue<<<nblk, 128, 0, stream>>>(feat, rt1, b1, out, N, 0);
    rgcn_gather<<<gblk, 256, 0, stream>>>(sorted, row_ptr, hb, out, N, 1);

    // ---- layer 2: out = gather(h2) + out@rt2 + b2 ----
    to_bf16<<<cblk, 256, 0, stream>>>(out, xb, N * DF / 8);
    mfma_transform<<<nblk, 256, 0, stream>>>(xb, wfrag + (size_t)8 * 8 * 64, hb, N);
    rgcn_root_epilogue<<<nblk, 128, 0, stream>>>(out, rt2, b2, out, N, 0);
    rgcn_gather<<<gblk, 256, 0, stream>>>(sorted, row_ptr, hb, out, N, 0);
    return;
  }

  // ---------------- fallback: atomic scatter ----------------
  size_t per_rel = ND * sizeof(unsigned short);
  size_t xmid_b = ND * sizeof(float);
  int RC = 1;
  if (ws_size > per_rel + xmid_b) {
    size_t rc = (ws_size - xmid_b) / per_rel;
    RC = rc >= NREL ? NREL : (int)rc;
  }
  unsigned short* hb = (unsigned short*)d_ws;
  float* xmid = (float*)((char*)d_ws + (size_t)RC * per_rel);
  const int sblk = (int)(((size_t)E * 16 + 255) / 256);

  for (int layer = 0; layer < 2; ++layer) {
    const float* xin = layer ? xmid : feat;
    const float* W   = layer ? W2 : W1;
    const float* rt  = layer ? rt2 : rt1;
    const float* bs  = layer ? b2 : b1;
    float* o         = layer ? out : xmid;

    hipMemsetAsync(o, 0, ND * sizeof(float), stream);
    for (int r0 = 0; r0 < NREL; r0 += RC) {
      int rc = (NREL - r0) < RC ? (NREL - r0) : RC;
      rgcn_transform<<<dim3(nblk, rc), 128, 0, stream>>>(
          xin, W + (size_t)r0 * DF * DF, nullptr, nullptr, hb, nullptr, N);
      rgcn_scatter<<<sblk, 256, 0, stream>>>(
          srcp, dstp, et, hb, o, E, N, r0, r0 + rc);
    }
    rgcn_root_epilogue<<<nblk, 128, 0, stream>>>(xin, rt, bs, o, N,
                                                 layer == 0 ? 1 : 2);
  }
}